// Round 1
// baseline (4824.632 us; speedup 1.0000x reference)
//
#include <hip/hip_runtime.h>
#include <math.h>
#include <stdint.h>

// ---------------- problem constants ----------------
#define CHH 100
#define CWW 152
#define NPIX 15200          // 100*152
#define NANCH 136800        // NPIX*9
#define NPRE 6000
#define NPOST 300
#define NCH 94              // ceil(6000/64)
#define CANDCAP 8192

// ---------------- ws layout (bytes) ----------------
#define WT_OFF   0ull                 // conv1 weights transposed: [4608][512] f32 = 9,437,184
#define WX_OFF   9437184ull           // 1x1 weights transposed: [512][54] f32 = 110,592
#define H_OFF    9547776ull           // hidden: [512][15200] f32 = 31,129,600
#define ROI_OFF  40677376ull          // roi: [136800][4] f32
#define SC_OFF   42866176ull          // sc: [136800] f32
#define CTL_OFF  43413376ull          // Ctl struct
#define CAND_OFF 43415424ull          // cand: [8192] u64
#define SBOX_OFF 43480960ull          // sorted boxes: [6000] float4

struct Ctl {
  unsigned hist[256];
  unsigned prefix;
  unsigned countGreater;
  unsigned candCount;
  unsigned pad;
};

struct AnchorArg { float v[36]; };

__device__ __forceinline__ unsigned mono_key(float f) {
  unsigned u = __float_as_uint(f);
  return u ^ ((u & 0x80000000u) ? 0xFFFFFFFFu : 0x80000000u);
}

// ---------------- K0: init control block ----------------
__global__ void initctl_kernel(Ctl* __restrict__ ctl) {
  int t = threadIdx.x;
  ctl->hist[t] = 0u;
  if (t == 0) { ctl->prefix = 0u; ctl->countGreater = 0u; ctl->candCount = 0u; }
}

// ---------------- K1: transpose conv1 weights [512][4608] -> [4608][512] ----------------
__global__ __launch_bounds__(256) void wtrans_kernel(const float* __restrict__ w, float* __restrict__ wT) {
  __shared__ float t[64][65];
  int k0  = blockIdx.x * 64;   // 72 tiles over K=4608
  int oc0 = blockIdx.y * 64;   // 8 tiles over OC=512
  int tid = threadIdx.x;
  #pragma unroll
  for (int r = 0; r < 16; ++r) {
    int li = r * 256 + tid; int rr = li >> 6, cc = li & 63;
    t[rr][cc] = w[(oc0 + rr) * 4608 + k0 + cc];           // coalesced over k
  }
  __syncthreads();
  #pragma unroll
  for (int r = 0; r < 16; ++r) {
    int li = r * 256 + tid; int rr = li >> 6, cc = li & 63;
    wT[(size_t)(k0 + rr) * 512 + oc0 + cc] = t[cc][rr];   // coalesced over oc
  }
}

// ---------------- K2: build combined 1x1 weights [512][54] (score 0..17, loc 18..53) -------
__global__ void wx_kernel(const float* __restrict__ score_w, const float* __restrict__ loc_w,
                          float* __restrict__ wx) {
  int i = blockIdx.x * 256 + threadIdx.x;
  if (i >= 512 * 54) return;
  int ic = i / 54, oc = i - ic * 54;
  wx[i] = (oc < 18) ? score_w[oc * 512 + ic] : loc_w[(oc - 18) * 512 + ic];
}

// ---------------- K3: conv1 3x3 pad1 + bias + ReLU ----------------
// block: 64 oc x (4y x 32x) pixels, 256 threads, K staged in chunks of 8 ic.
__global__ __launch_bounds__(256) void conv1_kernel(const float* __restrict__ x,
                                                    const float* __restrict__ wT,
                                                    const float* __restrict__ bias,
                                                    float* __restrict__ h) {
  __shared__ float wsm[72][64];          // [icc*9+tap][oc_local]
  __shared__ float ins[8][6][34];        // [icc][y(-1..4)][x(-1..32)]
  const int tid = threadIdx.x;
  const int x0 = blockIdx.x * 32, y0 = blockIdx.y * 4, oc0 = blockIdx.z * 64;
  const int xl = tid & 31;               // 0..31
  const int og = tid >> 5;               // 0..7 -> 8 consecutive oc
  float acc[8][4];
  #pragma unroll
  for (int i = 0; i < 8; ++i)
    #pragma unroll
    for (int y = 0; y < 4; ++y) acc[i][y] = 0.f;

  for (int ic0 = 0; ic0 < 512; ic0 += 8) {
    // stage weights: 72 consecutive K-rows (8 ic * 9 taps) x 64 oc
    #pragma unroll
    for (int r = 0; r < 18; ++r) {
      int li = r * 256 + tid;
      ((float*)wsm)[li] = wT[(size_t)(ic0 * 9 + (li >> 6)) * 512 + oc0 + (li & 63)];
    }
    // stage input patch 8 x 6 x 34 (zero-padded)
    #pragma unroll
    for (int r = 0; r < 7; ++r) {
      int li = r * 256 + tid;
      if (li < 1632) {
        int icl = li / 204; int rem = li - icl * 204;
        int ry = rem / 34;  int rx = rem - ry * 34;
        int gy = y0 + ry - 1, gx = x0 + rx - 1;
        float v = 0.f;
        if ((unsigned)gy < 100u && (unsigned)gx < 152u)
          v = x[(size_t)(ic0 + icl) * NPIX + gy * CWW + gx];
        ins[icl][ry][rx] = v;
      }
    }
    __syncthreads();
    #pragma unroll
    for (int icc = 0; icc < 8; ++icc) {
      float iv[3][6];
      #pragma unroll
      for (int kx = 0; kx < 3; ++kx)
        #pragma unroll
        for (int r = 0; r < 6; ++r) iv[kx][r] = ins[icc][r][xl + kx];
      #pragma unroll
      for (int ky = 0; ky < 3; ++ky)
        #pragma unroll
        for (int kx = 0; kx < 3; ++kx) {
          const float* wrow = &wsm[icc * 9 + ky * 3 + kx][og * 8];
          float4 wa = *(const float4*)(wrow);
          float4 wb = *(const float4*)(wrow + 4);
          #pragma unroll
          for (int y = 0; y < 4; ++y) {
            float v = iv[kx][y + ky];
            acc[0][y] += wa.x * v; acc[1][y] += wa.y * v;
            acc[2][y] += wa.z * v; acc[3][y] += wa.w * v;
            acc[4][y] += wb.x * v; acc[5][y] += wb.y * v;
            acc[6][y] += wb.z * v; acc[7][y] += wb.w * v;
          }
        }
    }
    __syncthreads();
  }
  // epilogue: bias + relu, coalesced stores
  #pragma unroll
  for (int i = 0; i < 8; ++i) {
    int oc = oc0 + og * 8 + i;
    float b = bias[oc];
    #pragma unroll
    for (int y = 0; y < 4; ++y) {
      int gx = x0 + xl, gy = y0 + y;
      if (gx < CWW) h[(size_t)oc * NPIX + gy * CWW + gx] = fmaxf(acc[i][y] + b, 0.f);
    }
  }
}

// ---------------- K4: 1x1 heads + softmax + loc2bbox + clip + valid ----------------
__global__ __launch_bounds__(256) void heads_kernel(const float* __restrict__ h,
                                                    const float* __restrict__ wx,
                                                    const float* __restrict__ score_b,
                                                    const float* __restrict__ loc_b,
                                                    float* __restrict__ rpn_loc,
                                                    float* __restrict__ rpn_score,
                                                    float* __restrict__ roi,
                                                    float* __restrict__ sc,
                                                    AnchorArg ab,
                                                    const int* __restrict__ ihp,
                                                    const int* __restrict__ iwp) {
  __shared__ float hs[64][64];
  __shared__ float red[54][64];
  const int tid = threadIdx.x;
  const int p0 = blockIdx.x * 64;
  const int pxl = tid & 63, icq = tid >> 6;   // icq uniform per wave
  float acc[54];
  #pragma unroll
  for (int o = 0; o < 54; ++o) acc[o] = 0.f;

  for (int c = 0; c < 8; ++c) {
    int ic0 = c * 64;
    #pragma unroll
    for (int r = 0; r < 16; ++r) {
      int li = r * 256 + tid; int i = li >> 6, lp = li & 63;
      int p = p0 + lp;
      hs[i][lp] = (p < NPIX) ? h[(size_t)(ic0 + i) * NPIX + p] : 0.f;
    }
    __syncthreads();
    #pragma unroll
    for (int k = 0; k < 16; ++k) {
      int icl = icq + k * 4;                   // wave-uniform -> scalar weight loads
      float v = hs[icl][pxl];
      const float* wrow = &wx[(ic0 + icl) * 54];
      #pragma unroll
      for (int o = 0; o < 54; ++o) acc[o] += wrow[o] * v;
    }
    __syncthreads();
  }
  // reduce the 4 ic-quarters (sequential waves, deterministic order)
  for (int w = 0; w < 4; ++w) {
    if (icq == w) {
      if (w == 0) {
        #pragma unroll
        for (int o = 0; o < 54; ++o) red[o][pxl] = acc[o];
      } else {
        #pragma unroll
        for (int o = 0; o < 54; ++o) red[o][pxl] += acc[o];
      }
    }
    __syncthreads();
  }

  const float fH = (float)(*ihp);
  const float fW = (float)(*iwp);
  for (int it = tid; it < 576; it += 256) {
    #pragma clang fp contract(off)
    int pl = it / 9, a = it - pl * 9;
    int p = p0 + pl;
    if (p >= NPIX) continue;
    float s0 = red[a * 2][pl]     + score_b[a * 2];
    float s1 = red[a * 2 + 1][pl] + score_b[a * 2 + 1];
    float dy = red[18 + a * 4][pl]     + loc_b[a * 4];
    float dx = red[18 + a * 4 + 1][pl] + loc_b[a * 4 + 1];
    float dh = red[18 + a * 4 + 2][pl] + loc_b[a * 4 + 2];
    float dw = red[18 + a * 4 + 3][pl] + loc_b[a * 4 + 3];
    int row = p * 9 + a;
    *(float2*)&rpn_score[row * 2] = make_float2(s0, s1);
    *(float4*)&rpn_loc[(size_t)row * 4] = make_float4(dy, dx, dh, dw);
    // anchor (matches _shifted_anchors fp32 op order)
    int ypix = p / CWW, xpix = p - ypix * CWW;
    float sy = (float)(ypix * 16), sx = (float)(xpix * 16);
    float a0 = sy + ab.v[a * 4 + 0], a1 = sx + ab.v[a * 4 + 1];
    float a2 = sy + ab.v[a * 4 + 2], a3 = sx + ab.v[a * 4 + 3];
    float ha = a2 - a0, wa = a3 - a1;
    float cy = a0 + 0.5f * ha, cx = a1 + 0.5f * wa;
    float cy2 = dy * ha + cy, cx2 = dx * wa + cx;
    float h2 = expf(dh) * ha, w2 = expf(dw) * wa;
    float y1 = cy2 - 0.5f * h2, x1 = cx2 - 0.5f * w2;
    float y2 = cy2 + 0.5f * h2, x2 = cx2 + 0.5f * w2;
    y1 = fminf(fmaxf(y1, 0.f), fH); x1 = fminf(fmaxf(x1, 0.f), fW);
    y2 = fminf(fmaxf(y2, 0.f), fH); x2 = fminf(fmaxf(x2, 0.f), fW);
    *(float4*)&roi[(size_t)row * 4] = make_float4(y1, x1, y2, x2);
    bool valid = (y2 - y1 >= 16.f) && (x2 - x1 >= 16.f);
    float m  = fmaxf(s0, s1);
    float e0 = expf(s0 - m), e1 = expf(s1 - m);
    float fg = e1 / (e0 + e1);
    sc[row] = valid ? fg : -__builtin_inff();
  }
}

// ---------------- K5/K6: radix-select (3 x 8-bit digits) for the 6000th score -------------
__global__ __launch_bounds__(256) void hist_pass(const float* __restrict__ sc,
                                                 Ctl* __restrict__ ctl, int pass) {
  __shared__ unsigned hloc[256];
  int tid = threadIdx.x;
  hloc[tid] = 0u;
  __syncthreads();
  unsigned prefix = ctl->prefix;
  for (int i = blockIdx.x * 256 + tid; i < NANCH; i += gridDim.x * 256) {
    unsigned m = mono_key(sc[i]);
    bool pred = (pass == 0) || ((m >> (32 - 8 * pass)) == prefix);
    if (pred) atomicAdd(&hloc[(m >> (24 - 8 * pass)) & 255u], 1u);
  }
  __syncthreads();
  if (hloc[tid]) atomicAdd(&ctl->hist[tid], hloc[tid]);
}

__global__ void scan_pass(Ctl* __restrict__ ctl) {
  __shared__ unsigned s[256];
  int t = threadIdx.x;
  s[t] = ctl->hist[t];
  ctl->hist[t] = 0u;                       // ready for next pass
  __syncthreads();
  for (int d = 1; d < 256; d <<= 1) {      // inclusive suffix sum
    unsigned v = s[t] + ((t + d < 256) ? s[t + d] : 0u);
    __syncthreads();
    s[t] = v;
    __syncthreads();
  }
  unsigned G = ctl->countGreater;
  unsigned inclT = s[t];
  unsigned inclN = (t < 255) ? s[t + 1] : 0u;
  if (G + inclT >= (unsigned)NPRE && G + inclN < (unsigned)NPRE) {
    ctl->prefix = (ctl->prefix << 8) | (unsigned)t;
    ctl->countGreater = G + inclN;
  }
}

// ---------------- K7: compact candidates (mono>>8 >= 24-bit prefix) ----------------
__global__ __launch_bounds__(256) void compact_kernel(const float* __restrict__ sc,
                                                      Ctl* __restrict__ ctl,
                                                      unsigned long long* __restrict__ cand) {
  int i = blockIdx.x * 256 + threadIdx.x;
  unsigned prefix = ctl->prefix;
  bool pred = false; unsigned m = 0;
  if (i < NANCH) { m = mono_key(sc[i]); pred = ((m >> 8) >= prefix); }
  unsigned long long mask = __ballot(pred);
  if (mask) {
    int lane = threadIdx.x & 63;
    int leader = __ffsll((long long)mask) - 1;
    unsigned base = 0;
    if (lane == leader) base = atomicAdd(&ctl->candCount, (unsigned)__popcll(mask));
    base = __shfl(base, leader);
    if (pred) {
      unsigned slot = base + (unsigned)__popcll(mask & ((1ull << lane) - 1ull));
      if (slot < CANDCAP)
        cand[slot] = (((unsigned long long)(~m)) << 32) | (unsigned)i;   // asc = (score desc, idx asc)
    }
  }
}

// ---------------- K8: single-block bitonic sort of <=8192 candidates; gather boxes --------
__global__ __launch_bounds__(1024) void sort_kernel(const unsigned long long* __restrict__ cand,
                                                    const Ctl* __restrict__ ctl,
                                                    const float* __restrict__ roi,
                                                    float4* __restrict__ sbox) {
  __shared__ unsigned long long s[8192];   // 64 KB
  int tid = threadIdx.x;
  unsigned cnt = ctl->candCount; if (cnt > CANDCAP) cnt = CANDCAP;
  #pragma unroll
  for (int r = 0; r < 8; ++r) {
    int i = r * 1024 + tid;
    s[i] = (i < (int)cnt) ? cand[i] : ~0ull;
  }
  __syncthreads();
  for (int k = 2; k <= 8192; k <<= 1)
    for (int j = k >> 1; j > 0; j >>= 1) {
      #pragma unroll
      for (int r = 0; r < 8; ++r) {
        int i = r * 1024 + tid; int l = i ^ j;
        if (l > i) {
          unsigned long long a = s[i], b = s[l];
          bool up = ((i & k) == 0);
          if ((a > b) == up) { s[i] = b; s[l] = a; }
        }
      }
      __syncthreads();
    }
  #pragma unroll
  for (int r = 0; r < 6; ++r) {
    int i = r * 1024 + tid;
    if (i < NPRE) {
      unsigned idx = (unsigned)(s[i] & 0xFFFFFFFFull);
      float4 b = make_float4(0.f, 0.f, 0.f, 0.f);
      if (idx < (unsigned)NANCH) b = *(const float4*)&roi[(size_t)idx * 4];
      sbox[i] = b;
    }
  }
}

// ---------------- K9: single-block greedy NMS + write rois ----------------
__device__ __forceinline__ bool iou_gt(float4 A, float4 B) {
  float areaA = (A.z - A.x) * (A.w - A.y);
  float areaB = (B.z - B.x) * (B.w - B.y);
  float ih = fmaxf(fminf(A.z, B.z) - fmaxf(A.x, B.x), 0.f);
  float iw = fmaxf(fminf(A.w, B.w) - fmaxf(A.y, B.y), 0.f);
  float inter = ih * iw;
  return inter / (areaA + areaB - inter + 1e-9f) > 0.7f;
}

__global__ __launch_bounds__(1024) void nms_kernel(const float4* __restrict__ sbox,
                                                   float* __restrict__ rois_out) {
  __shared__ float4 bs[3008];                 // 48 KB cache of first 3008 boxes
  __shared__ float4 cb[64];
  __shared__ unsigned long long diag[64];
  __shared__ unsigned long long remv[NCH];
  __shared__ int keepList[NPOST];
  __shared__ int keepCount;
  int tid = threadIdx.x, lane = tid & 63;
  for (int i = tid; i < 3008; i += 1024) bs[i] = sbox[i];
  if (tid < NCH) remv[tid] = (tid == NCH - 1) ? 0xFFFF000000000000ull : 0ull; // rows>=6000 removed
  __syncthreads();

  for (int c = 0; c < NCH; ++c) {
    if (tid < 64) {
      int i = c * 64 + tid;
      cb[tid] = (i < NPRE) ? ((i < 3008) ? bs[i] : sbox[i]) : make_float4(0.f, 0.f, 0.f, 0.f);
      diag[tid] = 0ull;
    }
    __syncthreads();
    {   // 64x64 diagonal IoU bits (j > i only)
      int l = tid >> 4, q = tid & 15;
      unsigned long long bits = 0ull;
      float4 bl = cb[l];
      #pragma unroll
      for (int s2 = 0; s2 < 4; ++s2) {
        int j = q * 4 + s2;
        if (j > l && c * 64 + j < NPRE && iou_gt(bl, cb[j])) bits |= (1ull << j);
      }
      if (bits) atomicOr(&diag[l], bits);
    }
    __syncthreads();
    if (tid < 64) {                          // serial greedy resolve within chunk (wave 0)
      unsigned long long dw = diag[tid];
      unsigned long long rem = remv[c];
      for (int k = 0; k < 64; ++k) {
        unsigned long long w = __shfl(dw, k);
        if (!((rem >> k) & 1ull)) rem |= w;
      }
      if (tid == 0) remv[c] = rem;
    }
    __syncthreads();
    unsigned long long kw = ~remv[c];        // kept rows of this chunk
    for (int jb = (c + 1) * 64 + tid; jb < 6016; jb += 1024) {  // waves 64-aligned
      bool sup = false;
      if (jb < NPRE) {
        float4 bj = (jb < 3008) ? bs[jb] : sbox[jb];
        unsigned long long k2 = kw;
        while (k2) {
          int r = __ffsll((long long)k2) - 1; k2 &= k2 - 1;
          if (iou_gt(cb[r], bj)) { sup = true; break; }
        }
      }
      unsigned long long w = __ballot(sup);
      if (lane == 0 && w) remv[jb >> 6] |= w;
    }
    __syncthreads();
  }

  if (tid == 0) {
    int cnt = 0;
    for (int c = 0; c < NCH && cnt < NPOST; ++c) {
      unsigned long long kw = ~remv[c];
      while (kw && cnt < NPOST) {
        int r = __ffsll((long long)kw) - 1; kw &= kw - 1;
        keepList[cnt++] = c * 64 + r;
      }
    }
    keepCount = cnt;
  }
  __syncthreads();
  for (int s2 = tid; s2 < NPOST; s2 += 1024) {
    float4 b = make_float4(0.f, 0.f, 0.f, 0.f);
    if (s2 < keepCount) { int i = keepList[s2]; b = (i < 3008) ? bs[i] : sbox[i]; }
    *(float4*)&rois_out[(size_t)s2 * 4] = b;
  }
}

// ---------------- host ----------------
extern "C" void kernel_launch(void* const* d_in, const int* in_sizes, int n_in,
                              void* d_out, int out_size, void* d_ws, size_t ws_size,
                              hipStream_t stream) {
  const float* x  = (const float*)d_in[0];
  const float* w1 = (const float*)d_in[1];
  const float* b1 = (const float*)d_in[2];
  const float* sw = (const float*)d_in[3];
  const float* sb = (const float*)d_in[4];
  const float* lw = (const float*)d_in[5];
  const float* lb = (const float*)d_in[6];
  const int* ihp  = (const int*)d_in[7];
  const int* iwp  = (const int*)d_in[8];
  float* out = (float*)d_out;

  char* ws = (char*)d_ws;
  float* wT   = (float*)(ws + WT_OFF);
  float* wx   = (float*)(ws + WX_OFF);
  float* h    = (float*)(ws + H_OFF);
  float* roi  = (float*)(ws + ROI_OFF);
  float* sc   = (float*)(ws + SC_OFF);
  Ctl*   ctl  = (Ctl*)(ws + CTL_OFF);
  unsigned long long* cand = (unsigned long long*)(ws + CAND_OFF);
  float4* sbox = (float4*)(ws + SBOX_OFF);

  // anchor base, double math then fp32 store (matches numpy)
  AnchorArg ab;
  {
    const double ratios[3] = {0.5, 1.0, 2.0};
    const double scales[3] = {8.0, 16.0, 32.0};
    for (int i = 0; i < 3; ++i)
      for (int j = 0; j < 3; ++j) {
        double hh = 16.0 * scales[j] * sqrt(ratios[i]);
        double wwd = 16.0 * scales[j] * sqrt(1.0 / ratios[i]);
        int a = i * 3 + j;
        ab.v[a * 4 + 0] = (float)(8.0 - hh / 2.0);
        ab.v[a * 4 + 1] = (float)(8.0 - wwd / 2.0);
        ab.v[a * 4 + 2] = (float)(8.0 + hh / 2.0);
        ab.v[a * 4 + 3] = (float)(8.0 + wwd / 2.0);
      }
  }

  float* rpn_loc   = out;                 // 136800*4
  float* rpn_score = out + 547200;        // 136800*2
  float* rois      = out + 820800;        // 300*4

  initctl_kernel<<<1, 256, 0, stream>>>(ctl);
  wtrans_kernel<<<dim3(72, 8), 256, 0, stream>>>(w1, wT);
  wx_kernel<<<108, 256, 0, stream>>>(sw, lw, wx);
  conv1_kernel<<<dim3(5, 25, 8), 256, 0, stream>>>(x, wT, b1, h);
  heads_kernel<<<238, 256, 0, stream>>>(h, wx, sb, lb, rpn_loc, rpn_score, roi, sc, ab, ihp, iwp);
  for (int p = 0; p < 3; ++p) {
    hist_pass<<<120, 256, 0, stream>>>(sc, ctl, p);
    scan_pass<<<1, 256, 0, stream>>>(ctl);
  }
  compact_kernel<<<535, 256, 0, stream>>>(sc, ctl, cand);
  sort_kernel<<<1, 1024, 0, stream>>>(cand, ctl, roi, sbox);
  nms_kernel<<<1, 1024, 0, stream>>>(sbox, rois);
}

// Round 2
// 2760.229 us; speedup vs baseline: 1.7479x; 1.7479x over previous
//
#include <hip/hip_runtime.h>
#include <math.h>
#include <stdint.h>

// ---------------- problem constants ----------------
#define CHH 100
#define CWW 152
#define NPIX 15200          // 100*152
#define NANCH 136800        // NPIX*9
#define NPRE 6000
#define NPOST 300
#define CANDCAP 8192
#define MROW 96             // u64 words per mask row (94 used, padded)

// ---------------- ws layout (bytes) ----------------
#define WT_OFF   0ull                 // conv1 weights transposed: [4608][512] f32 = 9,437,184
#define WX_OFF   9437184ull           // 1x1 weights transposed: [512][54] f32 = 110,592
#define H_OFF    9547776ull           // hidden: [512][15200] f32 = 31,129,600 (reused as NMS mask after heads)
#define ROI_OFF  40677376ull          // roi: [136800][4] f32
#define SC_OFF   42866176ull          // sc: [136800] f32
#define CTL_OFF  43413376ull          // Ctl struct
#define CAND_OFF 43415424ull          // cand: [8192] u64
#define SBOX_OFF 43480960ull          // sorted boxes: [6000] float4

struct Ctl {
  unsigned hist[256];
  unsigned prefix;
  unsigned countGreater;
  unsigned candCount;
  unsigned pad;
};

struct AnchorArg { float v[36]; };

__device__ __forceinline__ unsigned mono_key(float f) {
  unsigned u = __float_as_uint(f);
  return u ^ ((u & 0x80000000u) ? 0xFFFFFFFFu : 0x80000000u);
}

// ---------------- K0: init control block ----------------
__global__ void initctl_kernel(Ctl* __restrict__ ctl) {
  int t = threadIdx.x;
  ctl->hist[t] = 0u;
  if (t == 0) { ctl->prefix = 0u; ctl->countGreater = 0u; ctl->candCount = 0u; }
}

// ---------------- K1: transpose conv1 weights [512][4608] -> [4608][512] ----------------
__global__ __launch_bounds__(256) void wtrans_kernel(const float* __restrict__ w, float* __restrict__ wT) {
  __shared__ float t[64][65];
  int k0  = blockIdx.x * 64;   // 72 tiles over K=4608
  int oc0 = blockIdx.y * 64;   // 8 tiles over OC=512
  int tid = threadIdx.x;
  #pragma unroll
  for (int r = 0; r < 16; ++r) {
    int li = r * 256 + tid; int rr = li >> 6, cc = li & 63;
    t[rr][cc] = w[(oc0 + rr) * 4608 + k0 + cc];           // coalesced over k
  }
  __syncthreads();
  #pragma unroll
  for (int r = 0; r < 16; ++r) {
    int li = r * 256 + tid; int rr = li >> 6, cc = li & 63;
    wT[(size_t)(k0 + rr) * 512 + oc0 + cc] = t[cc][rr];   // coalesced over oc
  }
}

// ---------------- K2: build combined 1x1 weights [512][54] (score 0..17, loc 18..53) -------
__global__ void wx_kernel(const float* __restrict__ score_w, const float* __restrict__ loc_w,
                          float* __restrict__ wx) {
  int i = blockIdx.x * 256 + threadIdx.x;
  if (i >= 512 * 54) return;
  int ic = i / 54, oc = i - ic * 54;
  wx[i] = (oc < 18) ? score_w[oc * 512 + ic] : loc_w[(oc - 18) * 512 + ic];
}

// ---------------- K3: conv1 3x3 pad1 + bias + ReLU ----------------
__global__ __launch_bounds__(256) void conv1_kernel(const float* __restrict__ x,
                                                    const float* __restrict__ wT,
                                                    const float* __restrict__ bias,
                                                    float* __restrict__ h) {
  __shared__ float wsm[72][64];          // [icc*9+tap][oc_local]
  __shared__ float ins[8][6][34];        // [icc][y(-1..4)][x(-1..32)]
  const int tid = threadIdx.x;
  const int x0 = blockIdx.x * 32, y0 = blockIdx.y * 4, oc0 = blockIdx.z * 64;
  const int xl = tid & 31;               // 0..31
  const int og = tid >> 5;               // 0..7 -> 8 consecutive oc
  float acc[8][4];
  #pragma unroll
  for (int i = 0; i < 8; ++i)
    #pragma unroll
    for (int y = 0; y < 4; ++y) acc[i][y] = 0.f;

  for (int ic0 = 0; ic0 < 512; ic0 += 8) {
    #pragma unroll
    for (int r = 0; r < 18; ++r) {
      int li = r * 256 + tid;
      ((float*)wsm)[li] = wT[(size_t)(ic0 * 9 + (li >> 6)) * 512 + oc0 + (li & 63)];
    }
    #pragma unroll
    for (int r = 0; r < 7; ++r) {
      int li = r * 256 + tid;
      if (li < 1632) {
        int icl = li / 204; int rem = li - icl * 204;
        int ry = rem / 34;  int rx = rem - ry * 34;
        int gy = y0 + ry - 1, gx = x0 + rx - 1;
        float v = 0.f;
        if ((unsigned)gy < 100u && (unsigned)gx < 152u)
          v = x[(size_t)(ic0 + icl) * NPIX + gy * CWW + gx];
        ins[icl][ry][rx] = v;
      }
    }
    __syncthreads();
    #pragma unroll
    for (int icc = 0; icc < 8; ++icc) {
      float iv[3][6];
      #pragma unroll
      for (int kx = 0; kx < 3; ++kx)
        #pragma unroll
        for (int r = 0; r < 6; ++r) iv[kx][r] = ins[icc][r][xl + kx];
      #pragma unroll
      for (int ky = 0; ky < 3; ++ky)
        #pragma unroll
        for (int kx = 0; kx < 3; ++kx) {
          const float* wrow = &wsm[icc * 9 + ky * 3 + kx][og * 8];
          float4 wa = *(const float4*)(wrow);
          float4 wb = *(const float4*)(wrow + 4);
          #pragma unroll
          for (int y = 0; y < 4; ++y) {
            float v = iv[kx][y + ky];
            acc[0][y] += wa.x * v; acc[1][y] += wa.y * v;
            acc[2][y] += wa.z * v; acc[3][y] += wa.w * v;
            acc[4][y] += wb.x * v; acc[5][y] += wb.y * v;
            acc[6][y] += wb.z * v; acc[7][y] += wb.w * v;
          }
        }
    }
    __syncthreads();
  }
  #pragma unroll
  for (int i = 0; i < 8; ++i) {
    int oc = oc0 + og * 8 + i;
    float b = bias[oc];
    #pragma unroll
    for (int y = 0; y < 4; ++y) {
      int gx = x0 + xl, gy = y0 + y;
      if (gx < CWW) h[(size_t)oc * NPIX + gy * CWW + gx] = fmaxf(acc[i][y] + b, 0.f);
    }
  }
}

// ---------------- K4: 1x1 heads + softmax + loc2bbox + clip + valid ----------------
__global__ __launch_bounds__(256) void heads_kernel(const float* __restrict__ h,
                                                    const float* __restrict__ wx,
                                                    const float* __restrict__ score_b,
                                                    const float* __restrict__ loc_b,
                                                    float* __restrict__ rpn_loc,
                                                    float* __restrict__ rpn_score,
                                                    float* __restrict__ roi,
                                                    float* __restrict__ sc,
                                                    AnchorArg ab,
                                                    const int* __restrict__ ihp,
                                                    const int* __restrict__ iwp) {
  __shared__ float hs[64][64];
  __shared__ float red[54][64];
  const int tid = threadIdx.x;
  const int p0 = blockIdx.x * 64;
  const int pxl = tid & 63, icq = tid >> 6;   // icq uniform per wave
  float acc[54];
  #pragma unroll
  for (int o = 0; o < 54; ++o) acc[o] = 0.f;

  for (int c = 0; c < 8; ++c) {
    int ic0 = c * 64;
    #pragma unroll
    for (int r = 0; r < 16; ++r) {
      int li = r * 256 + tid; int i = li >> 6, lp = li & 63;
      int p = p0 + lp;
      hs[i][lp] = (p < NPIX) ? h[(size_t)(ic0 + i) * NPIX + p] : 0.f;
    }
    __syncthreads();
    #pragma unroll
    for (int k = 0; k < 16; ++k) {
      int icl = icq + k * 4;
      float v = hs[icl][pxl];
      const float* wrow = &wx[(ic0 + icl) * 54];
      #pragma unroll
      for (int o = 0; o < 54; ++o) acc[o] += wrow[o] * v;
    }
    __syncthreads();
  }
  for (int w = 0; w < 4; ++w) {
    if (icq == w) {
      if (w == 0) {
        #pragma unroll
        for (int o = 0; o < 54; ++o) red[o][pxl] = acc[o];
      } else {
        #pragma unroll
        for (int o = 0; o < 54; ++o) red[o][pxl] += acc[o];
      }
    }
    __syncthreads();
  }

  const float fH = (float)(*ihp);
  const float fW = (float)(*iwp);
  for (int it = tid; it < 576; it += 256) {
    #pragma clang fp contract(off)
    int pl = it / 9, a = it - pl * 9;
    int p = p0 + pl;
    if (p >= NPIX) continue;
    float s0 = red[a * 2][pl]     + score_b[a * 2];
    float s1 = red[a * 2 + 1][pl] + score_b[a * 2 + 1];
    float dy = red[18 + a * 4][pl]     + loc_b[a * 4];
    float dx = red[18 + a * 4 + 1][pl] + loc_b[a * 4 + 1];
    float dh = red[18 + a * 4 + 2][pl] + loc_b[a * 4 + 2];
    float dw = red[18 + a * 4 + 3][pl] + loc_b[a * 4 + 3];
    int row = p * 9 + a;
    *(float2*)&rpn_score[row * 2] = make_float2(s0, s1);
    *(float4*)&rpn_loc[(size_t)row * 4] = make_float4(dy, dx, dh, dw);
    int ypix = p / CWW, xpix = p - ypix * CWW;
    float sy = (float)(ypix * 16), sx = (float)(xpix * 16);
    float a0 = sy + ab.v[a * 4 + 0], a1 = sx + ab.v[a * 4 + 1];
    float a2 = sy + ab.v[a * 4 + 2], a3 = sx + ab.v[a * 4 + 3];
    float ha = a2 - a0, wa = a3 - a1;
    float cy = a0 + 0.5f * ha, cx = a1 + 0.5f * wa;
    float cy2 = dy * ha + cy, cx2 = dx * wa + cx;
    float h2 = expf(dh) * ha, w2 = expf(dw) * wa;
    float y1 = cy2 - 0.5f * h2, x1 = cx2 - 0.5f * w2;
    float y2 = cy2 + 0.5f * h2, x2 = cx2 + 0.5f * w2;
    y1 = fminf(fmaxf(y1, 0.f), fH); x1 = fminf(fmaxf(x1, 0.f), fW);
    y2 = fminf(fmaxf(y2, 0.f), fH); x2 = fminf(fmaxf(x2, 0.f), fW);
    *(float4*)&roi[(size_t)row * 4] = make_float4(y1, x1, y2, x2);
    bool valid = (y2 - y1 >= 16.f) && (x2 - x1 >= 16.f);
    float m  = fmaxf(s0, s1);
    float e0 = expf(s0 - m), e1 = expf(s1 - m);
    float fg = e1 / (e0 + e1);
    sc[row] = valid ? fg : -__builtin_inff();
  }
}

// ---------------- K5/K6: radix-select (3 x 8-bit digits) for the 6000th score -------------
__global__ __launch_bounds__(256) void hist_pass(const float* __restrict__ sc,
                                                 Ctl* __restrict__ ctl, int pass) {
  __shared__ unsigned hloc[256];
  int tid = threadIdx.x;
  hloc[tid] = 0u;
  __syncthreads();
  unsigned prefix = ctl->prefix;
  for (int i = blockIdx.x * 256 + tid; i < NANCH; i += gridDim.x * 256) {
    unsigned m = mono_key(sc[i]);
    bool pred = (pass == 0) || ((m >> (32 - 8 * pass)) == prefix);
    if (pred) atomicAdd(&hloc[(m >> (24 - 8 * pass)) & 255u], 1u);
  }
  __syncthreads();
  if (hloc[tid]) atomicAdd(&ctl->hist[tid], hloc[tid]);
}

__global__ void scan_pass(Ctl* __restrict__ ctl) {
  __shared__ unsigned s[256];
  int t = threadIdx.x;
  s[t] = ctl->hist[t];
  ctl->hist[t] = 0u;
  __syncthreads();
  for (int d = 1; d < 256; d <<= 1) {
    unsigned v = s[t] + ((t + d < 256) ? s[t + d] : 0u);
    __syncthreads();
    s[t] = v;
    __syncthreads();
  }
  unsigned G = ctl->countGreater;
  unsigned inclT = s[t];
  unsigned inclN = (t < 255) ? s[t + 1] : 0u;
  if (G + inclT >= (unsigned)NPRE && G + inclN < (unsigned)NPRE) {
    ctl->prefix = (ctl->prefix << 8) | (unsigned)t;
    ctl->countGreater = G + inclN;
  }
}

// ---------------- K7: compact candidates ----------------
__global__ __launch_bounds__(256) void compact_kernel(const float* __restrict__ sc,
                                                      Ctl* __restrict__ ctl,
                                                      unsigned long long* __restrict__ cand) {
  int i = blockIdx.x * 256 + threadIdx.x;
  unsigned prefix = ctl->prefix;
  bool pred = false; unsigned m = 0;
  if (i < NANCH) { m = mono_key(sc[i]); pred = ((m >> 8) >= prefix); }
  unsigned long long mask = __ballot(pred);
  if (mask) {
    int lane = threadIdx.x & 63;
    int leader = __ffsll((long long)mask) - 1;
    unsigned base = 0;
    if (lane == leader) base = atomicAdd(&ctl->candCount, (unsigned)__popcll(mask));
    base = __shfl(base, leader);
    if (pred) {
      unsigned slot = base + (unsigned)__popcll(mask & ((1ull << lane) - 1ull));
      if (slot < CANDCAP)
        cand[slot] = (((unsigned long long)(~m)) << 32) | (unsigned)i;
    }
  }
}

// ---------------- K8: single-block bitonic sort; gather boxes ----------------
__global__ __launch_bounds__(1024) void sort_kernel(const unsigned long long* __restrict__ cand,
                                                    const Ctl* __restrict__ ctl,
                                                    const float* __restrict__ roi,
                                                    float4* __restrict__ sbox) {
  __shared__ unsigned long long s[8192];
  int tid = threadIdx.x;
  unsigned cnt = ctl->candCount; if (cnt > CANDCAP) cnt = CANDCAP;
  #pragma unroll
  for (int r = 0; r < 8; ++r) {
    int i = r * 1024 + tid;
    s[i] = (i < (int)cnt) ? cand[i] : ~0ull;
  }
  __syncthreads();
  for (int k = 2; k <= 8192; k <<= 1)
    for (int j = k >> 1; j > 0; j >>= 1) {
      #pragma unroll
      for (int r = 0; r < 8; ++r) {
        int i = r * 1024 + tid; int l = i ^ j;
        if (l > i) {
          unsigned long long a = s[i], b = s[l];
          bool up = ((i & k) == 0);
          if ((a > b) == up) { s[i] = b; s[l] = a; }
        }
      }
      __syncthreads();
    }
  #pragma unroll
  for (int r = 0; r < 6; ++r) {
    int i = r * 1024 + tid;
    if (i < NPRE) {
      unsigned idx = (unsigned)(s[i] & 0xFFFFFFFFull);
      float4 b = make_float4(0.f, 0.f, 0.f, 0.f);
      if (idx < (unsigned)NANCH) b = *(const float4*)&roi[(size_t)idx * 4];
      sbox[i] = b;
    }
  }
}

// ---------------- K9a: parallel IoU mask matrix (torchvision-style) ----------------
__device__ __forceinline__ bool iou_gt(float4 A, float4 B) {
  float areaA = (A.z - A.x) * (A.w - A.y);
  float areaB = (B.z - B.x) * (B.w - B.y);
  float ih = fmaxf(fminf(A.z, B.z) - fmaxf(A.x, B.x), 0.f);
  float iw = fmaxf(fminf(A.w, B.w) - fmaxf(A.y, B.y), 0.f);
  float inter = ih * iw;
  return inter / (areaA + areaB - inter + 1e-9f) > 0.7f;
}

__global__ __launch_bounds__(256) void mask_kernel(const float4* __restrict__ sbox,
                                                   unsigned long long* __restrict__ M) {
  __shared__ float4 rb[64];
  __shared__ float4 cbx[256];
  const int c = blockIdx.x;            // row chunk 0..93
  const int tid = threadIdx.x;
  if (tid < 64) {
    int i = c * 64 + tid;
    rb[tid] = (i < NPRE) ? sbox[i] : make_float4(0.f, 0.f, 0.f, 0.f);
  }
  __syncthreads();
  const int rl = tid >> 2, q = tid & 3;
  const int i = c * 64 + rl;
  const float4 bi = rb[rl];
  for (int t = c >> 2; t < 24; ++t) {
    int j = t * 256 + tid;
    cbx[tid] = (j < NPRE) ? sbox[j] : make_float4(0.f, 0.f, 0.f, 0.f);
    __syncthreads();
    int w = t * 4 + q;
    if (w >= c && i < NPRE) {
      unsigned long long bits = 0ull;
      #pragma unroll 8
      for (int jj = 0; jj < 64; ++jj) {
        int jg = w * 64 + jj;
        float4 bj = cbx[q * 64 + jj];
        if (jg > i && jg < NPRE && iou_gt(bi, bj)) bits |= (1ull << jj);
      }
      M[(size_t)i * MROW + w] = bits;
    }
    __syncthreads();
  }
}

// ---------------- K9b: serial greedy resolve (1 wave, mask words 2/lane) --------------
__global__ __launch_bounds__(64) void resolve_kernel(const unsigned long long* __restrict__ M,
                                                     const Ctl* __restrict__ ctl,
                                                     const float4* __restrict__ sbox,
                                                     float* __restrict__ rois_out) {
  __shared__ unsigned long long remLDS[94];
  __shared__ int keepList[NPOST];
  __shared__ int keepCount;
  const int l = threadIdx.x;
  unsigned cnt = ctl->candCount; if (cnt > (unsigned)NPRE) cnt = NPRE;
  const int nvalid = (int)cnt;

  auto initw = [&](int w) -> unsigned long long {
    int lo = w * 64;
    if (lo + 64 <= nvalid) return 0ull;
    if (lo >= nvalid) return ~0ull;
    return (~0ull) << (nvalid - lo);
  };
  unsigned long long rem0 = initw(l);                       // word l
  unsigned long long rem1 = (l < 30) ? initw(64 + l) : ~0ull; // word 64+l

  auto loadg = [&](int g, unsigned long long* m0, unsigned long long* m1) {
    #pragma unroll
    for (int r = 0; r < 8; ++r) {
      int i = g * 8 + r;
      if (i < NPRE) {
        m0[r] = M[(size_t)i * MROW + l];
        m1[r] = (l < 30) ? M[(size_t)i * MROW + 64 + l] : 0ull;
      } else { m0[r] = 0ull; m1[r] = 0ull; }
    }
  };
  auto procg = [&](int g, unsigned long long* m0, unsigned long long* m1) {
    #pragma unroll
    for (int r = 0; r < 8; ++r) {
      int i = g * 8 + r;
      int ci = i >> 6, bit = i & 63;
      unsigned long long wv = (ci < 64) ? rem0 : rem1;
      int owner = (ci < 64) ? ci : (ci - 64);
      int rbit = __shfl((int)((wv >> bit) & 1ull), owner);
      if (!rbit) {   // row i kept -> suppress its mask (only words >= ci matter)
        rem0 |= (l >= ci) ? m0[r] : 0ull;
        rem1 |= ((64 + l) >= ci) ? m1[r] : 0ull;
      }
    }
  };

  unsigned long long A0[8], A1[8], B0[8], B1[8], C0[8], C1[8], D0[8], D1[8];
  loadg(0, A0, A1); loadg(1, B0, B1); loadg(2, C0, C1); loadg(3, D0, D1);
  for (int g = 0; g < 752; g += 4) {   // 752*8 = 6016 rows (tail rows are pre-removed)
    procg(g,     A0, A1); if (g + 4 < 752) loadg(g + 4, A0, A1);
    procg(g + 1, B0, B1); if (g + 5 < 752) loadg(g + 5, B0, B1);
    procg(g + 2, C0, C1); if (g + 6 < 752) loadg(g + 6, C0, C1);
    procg(g + 3, D0, D1); if (g + 7 < 752) loadg(g + 7, D0, D1);
  }

  remLDS[l] = rem0;
  if (l < 30) remLDS[64 + l] = rem1;
  __syncthreads();
  if (l == 0) {
    int ck = 0;
    for (int w = 0; w < 94 && ck < NPOST; ++w) {
      unsigned long long kw = ~remLDS[w];
      while (kw && ck < NPOST) {
        int r = __ffsll((long long)kw) - 1; kw &= kw - 1;
        keepList[ck++] = w * 64 + r;
      }
    }
    keepCount = ck;
  }
  __syncthreads();
  for (int s = l; s < NPOST; s += 64) {
    float4 b = make_float4(0.f, 0.f, 0.f, 0.f);
    if (s < keepCount) b = sbox[keepList[s]];
    *(float4*)&rois_out[(size_t)s * 4] = b;
  }
}

// ---------------- host ----------------
extern "C" void kernel_launch(void* const* d_in, const int* in_sizes, int n_in,
                              void* d_out, int out_size, void* d_ws, size_t ws_size,
                              hipStream_t stream) {
  const float* x  = (const float*)d_in[0];
  const float* w1 = (const float*)d_in[1];
  const float* b1 = (const float*)d_in[2];
  const float* sw = (const float*)d_in[3];
  const float* sb = (const float*)d_in[4];
  const float* lw = (const float*)d_in[5];
  const float* lb = (const float*)d_in[6];
  const int* ihp  = (const int*)d_in[7];
  const int* iwp  = (const int*)d_in[8];
  float* out = (float*)d_out;

  char* ws = (char*)d_ws;
  float* wT   = (float*)(ws + WT_OFF);
  float* wx   = (float*)(ws + WX_OFF);
  float* h    = (float*)(ws + H_OFF);
  float* roi  = (float*)(ws + ROI_OFF);
  float* sc   = (float*)(ws + SC_OFF);
  Ctl*   ctl  = (Ctl*)(ws + CTL_OFF);
  unsigned long long* cand = (unsigned long long*)(ws + CAND_OFF);
  float4* sbox = (float4*)(ws + SBOX_OFF);
  // NMS mask matrix reuses the (dead-by-then) hidden-activation region
  unsigned long long* Mmask = (unsigned long long*)(ws + H_OFF);

  AnchorArg ab;
  {
    const double ratios[3] = {0.5, 1.0, 2.0};
    const double scales[3] = {8.0, 16.0, 32.0};
    for (int i = 0; i < 3; ++i)
      for (int j = 0; j < 3; ++j) {
        double hh = 16.0 * scales[j] * sqrt(ratios[i]);
        double wwd = 16.0 * scales[j] * sqrt(1.0 / ratios[i]);
        int a = i * 3 + j;
        ab.v[a * 4 + 0] = (float)(8.0 - hh / 2.0);
        ab.v[a * 4 + 1] = (float)(8.0 - wwd / 2.0);
        ab.v[a * 4 + 2] = (float)(8.0 + hh / 2.0);
        ab.v[a * 4 + 3] = (float)(8.0 + wwd / 2.0);
      }
  }

  float* rpn_loc   = out;                 // 136800*4
  float* rpn_score = out + 547200;        // 136800*2
  float* rois      = out + 820800;        // 300*4

  initctl_kernel<<<1, 256, 0, stream>>>(ctl);
  wtrans_kernel<<<dim3(72, 8), 256, 0, stream>>>(w1, wT);
  wx_kernel<<<108, 256, 0, stream>>>(sw, lw, wx);
  conv1_kernel<<<dim3(5, 25, 8), 256, 0, stream>>>(x, wT, b1, h);
  heads_kernel<<<238, 256, 0, stream>>>(h, wx, sb, lb, rpn_loc, rpn_score, roi, sc, ab, ihp, iwp);
  for (int p = 0; p < 3; ++p) {
    hist_pass<<<120, 256, 0, stream>>>(sc, ctl, p);
    scan_pass<<<1, 256, 0, stream>>>(ctl);
  }
  compact_kernel<<<535, 256, 0, stream>>>(sc, ctl, cand);
  sort_kernel<<<1, 1024, 0, stream>>>(cand, ctl, roi, sbox);
  mask_kernel<<<94, 256, 0, stream>>>(sbox, Mmask);
  resolve_kernel<<<1, 64, 0, stream>>>(Mmask, ctl, sbox, rois);
}

// Round 3
// 1809.356 us; speedup vs baseline: 2.6665x; 1.5255x over previous
//
#include <hip/hip_runtime.h>
#include <math.h>
#include <stdint.h>

// ---------------- problem constants ----------------
#define CHH 100
#define CWW 152
#define NPIX 15200          // 100*152
#define NANCH 136800        // NPIX*9
#define NPRE 6000
#define NPOST 300
#define CANDCAP 8192
#define MROW 96             // u64 words per mask row (94 used, padded)

// padded pixel geometry for the MFMA conv: pp = (py+1)*154 + (px+1)
#define PSTRIDE 154
#define PPVALID 16016       // 154*104 region containing all shifted accesses
#define PPS 16128           // padded to 126 tiles of 128
#define XGUARD 256          // zero guard rows each side of the [0,PPS) range
#define XROWS_TOTAL (PPS + 2*XGUARD)   // 16640

// ---------------- ws layout (bytes) ----------------
#define WTH_OFF  0ull                  // w taps hi: [9][512][512] f16 = 4,718,592
#define WTL_OFF  4718592ull            // w taps lo
#define WX_OFF   9437184ull            // 1x1 weights transposed: [512][54] f32
#define XH_OFF   9547776ull            // x hi plane: [16640][512] f16 = 17,039,360
#define XL_OFF   26587136ull           // x lo plane
#define H_OFF    43626496ull           // hidden: [512][16128] f32 = 33,030,144 (reused as NMS mask)
#define ROI_OFF  76656640ull           // roi: [136800][4] f32
#define SC_OFF   78845440ull           // sc: [136800] f32
#define CTL_OFF  79392640ull           // Ctl struct
#define CAND_OFF 79396736ull           // cand: [8192] u64
#define SBOX_OFF 79462272ull           // sorted boxes: [6000] float4

typedef _Float16 f16x8 __attribute__((ext_vector_type(8)));
typedef float    f32x4 __attribute__((ext_vector_type(4)));

struct Ctl {
  unsigned hist[256];
  unsigned prefix;
  unsigned countGreater;
  unsigned candCount;
  unsigned pad;
};

struct AnchorArg { float v[36]; };

__device__ __forceinline__ unsigned mono_key(float f) {
  unsigned u = __float_as_uint(f);
  return u ^ ((u & 0x80000000u) ? 0xFFFFFFFFu : 0x80000000u);
}

// ---------------- K1: combined 1x1 weights + ctl init ----------------
__global__ void wx_kernel(const float* __restrict__ score_w, const float* __restrict__ loc_w,
                          float* __restrict__ wx, Ctl* __restrict__ ctl) {
  int i = blockIdx.x * 256 + threadIdx.x;
  if (blockIdx.x == 0) {
    int t = threadIdx.x;
    ctl->hist[t] = 0u;
    if (t == 0) { ctl->prefix = 0u; ctl->countGreater = 0u; ctl->candCount = 0u; }
  }
  if (i >= 512 * 54) return;
  int ic = i / 54, oc = i - ic * 54;
  wx[i] = (oc < 18) ? score_w[oc * 512 + ic] : loc_w[(oc - 18) * 512 + ic];
}

// ---------------- K2: split conv1 weights into per-tap f16 hi/lo planes ----------------
// w1 [oc][ic][ky][kx] -> wtapH/L [t][oc][ic], t = ky*3+kx
__global__ __launch_bounds__(256) void prep_w_kernel(const float* __restrict__ w1,
                                                     _Float16* __restrict__ wtapH,
                                                     _Float16* __restrict__ wtapL) {
  __shared__ float wl[4608];
  const int oc = blockIdx.x, tid = threadIdx.x;
  for (int li = tid; li < 4608; li += 256) wl[li] = w1[(size_t)oc * 4608 + li];
  __syncthreads();
  for (int t = 0; t < 9; ++t) {
    size_t ob = ((size_t)t * 512 + oc) * 512;
    for (int ic = tid; ic < 512; ic += 256) {
      float v = wl[ic * 9 + t];
      _Float16 hi = (_Float16)v;
      wtapH[ob + ic] = hi;
      wtapL[ob + ic] = (_Float16)(v - (float)hi);
    }
  }
}

// ---------------- K3: transpose+pad+split input: x [512][15200] -> xh/xl [16640][512] ----
__global__ __launch_bounds__(256) void prep_x_kernel(const float* __restrict__ x,
                                                     _Float16* __restrict__ xh,
                                                     _Float16* __restrict__ xl) {
  __shared__ float tile[64][65];
  const int tid = threadIdx.x;
  const int r0 = blockIdx.x * 64;                // alloc-row base (0..16640)
  for (int ic0 = 0; ic0 < 512; ic0 += 64) {
    #pragma unroll
    for (int it = 0; it < 16; ++it) {
      int li = it * 256 + tid;
      int i = li >> 6, j = li & 63;
      int pp = r0 + j - XGUARD;
      float v = 0.f;
      if (pp >= 0 && pp < PPVALID) {
        int rowp = pp / PSTRIDE, colp = pp - rowp * PSTRIDE;
        if (rowp >= 1 && rowp <= 100 && colp >= 1 && colp <= 152) {
          int p = (rowp - 1) * CWW + (colp - 1);
          v = x[(size_t)(ic0 + i) * NPIX + p];
        }
      }
      tile[i][j] = v;
    }
    __syncthreads();
    int j = tid >> 2, cq = tid & 3;
    size_t ob = (size_t)(r0 + j) * 512 + ic0 + cq * 16;
    #pragma unroll
    for (int c = 0; c < 16; ++c) {
      float v = tile[cq * 16 + c][j];
      _Float16 hi = (_Float16)v;
      xh[ob + c] = hi;
      xl[ob + c] = (_Float16)(v - (float)hi);
    }
    __syncthreads();
  }
}

// ---------------- K4: conv1 as split-f16 MFMA implicit GEMM ----------------
// C[oc][pp] = sum_{t,ic} W_t[oc][ic] * X[pp+shift_t][ic], 128x128 tile, 4 waves.
__global__ __launch_bounds__(256) void conv1_mfma_kernel(const _Float16* __restrict__ xh,
                                                         const _Float16* __restrict__ xl,
                                                         const _Float16* __restrict__ wtapH,
                                                         const _Float16* __restrict__ wtapL,
                                                         const float* __restrict__ bias,
                                                         float* __restrict__ h) {
  __shared__ _Float16 Ah[128][32], Al[128][32], Bh[128][32], Bl[128][32];
  __shared__ float bsm[128];
  const int tid = threadIdx.x;
  const int pp0 = blockIdx.x * 128;
  const int oc0 = blockIdx.y * 128;
  if (tid < 128) bsm[tid] = bias[oc0 + tid];

  const int lane = tid & 63;
  const int n16 = lane & 15, quad = lane >> 4;
  const int wid = tid >> 6;
  const int wm = wid >> 1, wn = wid & 1;
  const int srow = tid >> 2, sq = tid & 3;       // staging: row 0..63, 16B chunk 0..3

  f32x4 acc[4][4];
  #pragma unroll
  for (int mi = 0; mi < 4; ++mi)
    #pragma unroll
    for (int ni = 0; ni < 4; ++ni) acc[mi][ni] = (f32x4){0.f, 0.f, 0.f, 0.f};

  for (int t = 0; t < 9; ++t) {
    const int dsh = (t / 3 - 1) * PSTRIDE + (t % 3) - 1;
    const size_t wbase = ((size_t)t * 512 + oc0) * 512;
    for (int icb = 0; icb < 512; icb += 32) {
      // stage A (weights) and B (input) hi/lo tiles: [128 rows][32 ic]
      #pragma unroll
      for (int hf = 0; hf < 2; ++hf) {
        int row = hf * 64 + srow;
        size_t wo = wbase + (size_t)row * 512 + icb + sq * 8;
        *(f16x8*)&Ah[row][sq * 8] = *(const f16x8*)&wtapH[wo];
        *(f16x8*)&Al[row][sq * 8] = *(const f16x8*)&wtapL[wo];
        size_t xo = (size_t)(pp0 + row + dsh) * 512 + icb + sq * 8;
        *(f16x8*)&Bh[row][sq * 8] = *(const f16x8*)&xh[xo];
        *(f16x8*)&Bl[row][sq * 8] = *(const f16x8*)&xl[xo];
      }
      __syncthreads();
      f16x8 ah[4], al[4], bh[4], bl[4];
      #pragma unroll
      for (int mi = 0; mi < 4; ++mi) {
        ah[mi] = *(const f16x8*)&Ah[wm * 64 + mi * 16 + n16][quad * 8];
        al[mi] = *(const f16x8*)&Al[wm * 64 + mi * 16 + n16][quad * 8];
      }
      #pragma unroll
      for (int ni = 0; ni < 4; ++ni) {
        bh[ni] = *(const f16x8*)&Bh[wn * 64 + ni * 16 + n16][quad * 8];
        bl[ni] = *(const f16x8*)&Bl[wn * 64 + ni * 16 + n16][quad * 8];
      }
      #pragma unroll
      for (int mi = 0; mi < 4; ++mi)
        #pragma unroll
        for (int ni = 0; ni < 4; ++ni) {
          acc[mi][ni] = __builtin_amdgcn_mfma_f32_16x16x32_f16(ah[mi], bh[ni], acc[mi][ni], 0, 0, 0);
          acc[mi][ni] = __builtin_amdgcn_mfma_f32_16x16x32_f16(ah[mi], bl[ni], acc[mi][ni], 0, 0, 0);
          acc[mi][ni] = __builtin_amdgcn_mfma_f32_16x16x32_f16(al[mi], bh[ni], acc[mi][ni], 0, 0, 0);
        }
      __syncthreads();
    }
  }
  // epilogue: bias + relu; C/D layout: col=lane&15 (pix), row=quad*4+reg (oc)
  #pragma unroll
  for (int mi = 0; mi < 4; ++mi) {
    int ocb = wm * 64 + mi * 16 + quad * 4;
    #pragma unroll
    for (int ni = 0; ni < 4; ++ni) {
      int pp = pp0 + wn * 64 + ni * 16 + n16;
      #pragma unroll
      for (int r = 0; r < 4; ++r) {
        float v = acc[mi][ni][r] + bsm[ocb + r];
        h[(size_t)(oc0 + ocb + r) * PPS + pp] = fmaxf(v, 0.f);
      }
    }
  }
}

// ---------------- K5: 1x1 heads + softmax + loc2bbox + clip + valid ----------------
__global__ __launch_bounds__(256) void heads_kernel(const float* __restrict__ h,
                                                    const float* __restrict__ wx,
                                                    const float* __restrict__ score_b,
                                                    const float* __restrict__ loc_b,
                                                    float* __restrict__ rpn_loc,
                                                    float* __restrict__ rpn_score,
                                                    float* __restrict__ roi,
                                                    float* __restrict__ sc,
                                                    AnchorArg ab,
                                                    const int* __restrict__ ihp,
                                                    const int* __restrict__ iwp) {
  __shared__ float hs[64][64];
  __shared__ float red[54][64];
  const int tid = threadIdx.x;
  const int p0 = blockIdx.x * 64;
  const int pxl = tid & 63, icq = tid >> 6;   // icq uniform per wave
  // padded-geometry address of this thread's pixel column
  int pcol = p0 + pxl;
  bool pok = pcol < NPIX;
  int ppl = 0;
  if (pok) ppl = (pcol / CWW + 1) * PSTRIDE + (pcol % CWW) + 1;

  float acc[54];
  #pragma unroll
  for (int o = 0; o < 54; ++o) acc[o] = 0.f;

  for (int c = 0; c < 8; ++c) {
    int ic0 = c * 64;
    #pragma unroll
    for (int r = 0; r < 16; ++r) {
      int i = r * 4 + icq;
      hs[i][pxl] = pok ? h[(size_t)(ic0 + i) * PPS + ppl] : 0.f;
    }
    __syncthreads();
    #pragma unroll
    for (int k = 0; k < 16; ++k) {
      int icl = icq + k * 4;
      float v = hs[icl][pxl];
      const float* wrow = &wx[(ic0 + icl) * 54];
      #pragma unroll
      for (int o = 0; o < 54; ++o) acc[o] += wrow[o] * v;
    }
    __syncthreads();
  }
  for (int w = 0; w < 4; ++w) {
    if (icq == w) {
      if (w == 0) {
        #pragma unroll
        for (int o = 0; o < 54; ++o) red[o][pxl] = acc[o];
      } else {
        #pragma unroll
        for (int o = 0; o < 54; ++o) red[o][pxl] += acc[o];
      }
    }
    __syncthreads();
  }

  const float fH = (float)(*ihp);
  const float fW = (float)(*iwp);
  for (int it = tid; it < 576; it += 256) {
    #pragma clang fp contract(off)
    int pl = it / 9, a = it - pl * 9;
    int p = p0 + pl;
    if (p >= NPIX) continue;
    float s0 = red[a * 2][pl]     + score_b[a * 2];
    float s1 = red[a * 2 + 1][pl] + score_b[a * 2 + 1];
    float dy = red[18 + a * 4][pl]     + loc_b[a * 4];
    float dx = red[18 + a * 4 + 1][pl] + loc_b[a * 4 + 1];
    float dh = red[18 + a * 4 + 2][pl] + loc_b[a * 4 + 2];
    float dw = red[18 + a * 4 + 3][pl] + loc_b[a * 4 + 3];
    int row = p * 9 + a;
    *(float2*)&rpn_score[row * 2] = make_float2(s0, s1);
    *(float4*)&rpn_loc[(size_t)row * 4] = make_float4(dy, dx, dh, dw);
    int ypix = p / CWW, xpix = p - ypix * CWW;
    float sy = (float)(ypix * 16), sx = (float)(xpix * 16);
    float a0 = sy + ab.v[a * 4 + 0], a1 = sx + ab.v[a * 4 + 1];
    float a2 = sy + ab.v[a * 4 + 2], a3 = sx + ab.v[a * 4 + 3];
    float ha = a2 - a0, wa = a3 - a1;
    float cy = a0 + 0.5f * ha, cx = a1 + 0.5f * wa;
    float cy2 = dy * ha + cy, cx2 = dx * wa + cx;
    float h2 = expf(dh) * ha, w2 = expf(dw) * wa;
    float y1 = cy2 - 0.5f * h2, x1 = cx2 - 0.5f * w2;
    float y2 = cy2 + 0.5f * h2, x2 = cx2 + 0.5f * w2;
    y1 = fminf(fmaxf(y1, 0.f), fH); x1 = fminf(fmaxf(x1, 0.f), fW);
    y2 = fminf(fmaxf(y2, 0.f), fH); x2 = fminf(fmaxf(x2, 0.f), fW);
    *(float4*)&roi[(size_t)row * 4] = make_float4(y1, x1, y2, x2);
    bool valid = (y2 - y1 >= 16.f) && (x2 - x1 >= 16.f);
    float m  = fmaxf(s0, s1);
    float e0 = expf(s0 - m), e1 = expf(s1 - m);
    float fg = e1 / (e0 + e1);
    sc[row] = valid ? fg : -__builtin_inff();
  }
}

// ---------------- K6/K7: radix-select (3 x 8-bit digits) for the 6000th score -------------
__global__ __launch_bounds__(256) void hist_pass(const float* __restrict__ sc,
                                                 Ctl* __restrict__ ctl, int pass) {
  __shared__ unsigned hloc[256];
  int tid = threadIdx.x;
  hloc[tid] = 0u;
  __syncthreads();
  unsigned prefix = ctl->prefix;
  for (int i = blockIdx.x * 256 + tid; i < NANCH; i += gridDim.x * 256) {
    unsigned m = mono_key(sc[i]);
    bool pred = (pass == 0) || ((m >> (32 - 8 * pass)) == prefix);
    if (pred) atomicAdd(&hloc[(m >> (24 - 8 * pass)) & 255u], 1u);
  }
  __syncthreads();
  if (hloc[tid]) atomicAdd(&ctl->hist[tid], hloc[tid]);
}

__global__ void scan_pass(Ctl* __restrict__ ctl) {
  __shared__ unsigned s[256];
  int t = threadIdx.x;
  s[t] = ctl->hist[t];
  ctl->hist[t] = 0u;
  __syncthreads();
  for (int d = 1; d < 256; d <<= 1) {
    unsigned v = s[t] + ((t + d < 256) ? s[t + d] : 0u);
    __syncthreads();
    s[t] = v;
    __syncthreads();
  }
  unsigned G = ctl->countGreater;
  unsigned inclT = s[t];
  unsigned inclN = (t < 255) ? s[t + 1] : 0u;
  if (G + inclT >= (unsigned)NPRE && G + inclN < (unsigned)NPRE) {
    ctl->prefix = (ctl->prefix << 8) | (unsigned)t;
    ctl->countGreater = G + inclN;
  }
}

// ---------------- K8: compact candidates ----------------
__global__ __launch_bounds__(256) void compact_kernel(const float* __restrict__ sc,
                                                      Ctl* __restrict__ ctl,
                                                      unsigned long long* __restrict__ cand) {
  int i = blockIdx.x * 256 + threadIdx.x;
  unsigned prefix = ctl->prefix;
  bool pred = false; unsigned m = 0;
  if (i < NANCH) { m = mono_key(sc[i]); pred = ((m >> 8) >= prefix); }
  unsigned long long mask = __ballot(pred);
  if (mask) {
    int lane = threadIdx.x & 63;
    int leader = __ffsll((long long)mask) - 1;
    unsigned base = 0;
    if (lane == leader) base = atomicAdd(&ctl->candCount, (unsigned)__popcll(mask));
    base = __shfl(base, leader);
    if (pred) {
      unsigned slot = base + (unsigned)__popcll(mask & ((1ull << lane) - 1ull));
      if (slot < CANDCAP)
        cand[slot] = (((unsigned long long)(~m)) << 32) | (unsigned)i;
    }
  }
}

// ---------------- K9: single-block bitonic sort; gather boxes ----------------
__global__ __launch_bounds__(1024) void sort_kernel(const unsigned long long* __restrict__ cand,
                                                    const Ctl* __restrict__ ctl,
                                                    const float* __restrict__ roi,
                                                    float4* __restrict__ sbox) {
  __shared__ unsigned long long s[8192];
  int tid = threadIdx.x;
  unsigned cnt = ctl->candCount; if (cnt > CANDCAP) cnt = CANDCAP;
  #pragma unroll
  for (int r = 0; r < 8; ++r) {
    int i = r * 1024 + tid;
    s[i] = (i < (int)cnt) ? cand[i] : ~0ull;
  }
  __syncthreads();
  for (int k = 2; k <= 8192; k <<= 1)
    for (int j = k >> 1; j > 0; j >>= 1) {
      #pragma unroll
      for (int r = 0; r < 8; ++r) {
        int i = r * 1024 + tid; int l = i ^ j;
        if (l > i) {
          unsigned long long a = s[i], b = s[l];
          bool up = ((i & k) == 0);
          if ((a > b) == up) { s[i] = b; s[l] = a; }
        }
      }
      __syncthreads();
    }
  #pragma unroll
  for (int r = 0; r < 6; ++r) {
    int i = r * 1024 + tid;
    if (i < NPRE) {
      unsigned idx = (unsigned)(s[i] & 0xFFFFFFFFull);
      float4 b = make_float4(0.f, 0.f, 0.f, 0.f);
      if (idx < (unsigned)NANCH) b = *(const float4*)&roi[(size_t)idx * 4];
      sbox[i] = b;
    }
  }
}

// ---------------- K10a: parallel IoU mask matrix ----------------
__device__ __forceinline__ bool iou_gt(float4 A, float4 B) {
  float areaA = (A.z - A.x) * (A.w - A.y);
  float areaB = (B.z - B.x) * (B.w - B.y);
  float ih = fmaxf(fminf(A.z, B.z) - fmaxf(A.x, B.x), 0.f);
  float iw = fmaxf(fminf(A.w, B.w) - fmaxf(A.y, B.y), 0.f);
  float inter = ih * iw;
  return inter / (areaA + areaB - inter + 1e-9f) > 0.7f;
}

__global__ __launch_bounds__(256) void mask_kernel(const float4* __restrict__ sbox,
                                                   unsigned long long* __restrict__ M) {
  __shared__ float4 rb[64];
  __shared__ float4 cbx[256];
  const int c = blockIdx.x;
  const int tid = threadIdx.x;
  if (tid < 64) {
    int i = c * 64 + tid;
    rb[tid] = (i < NPRE) ? sbox[i] : make_float4(0.f, 0.f, 0.f, 0.f);
  }
  __syncthreads();
  const int rl = tid >> 2, q = tid & 3;
  const int i = c * 64 + rl;
  const float4 bi = rb[rl];
  for (int t = c >> 2; t < 24; ++t) {
    int j = t * 256 + tid;
    cbx[tid] = (j < NPRE) ? sbox[j] : make_float4(0.f, 0.f, 0.f, 0.f);
    __syncthreads();
    int w = t * 4 + q;
    if (w >= c && i < NPRE) {
      unsigned long long bits = 0ull;
      #pragma unroll 8
      for (int jj = 0; jj < 64; ++jj) {
        int jg = w * 64 + jj;
        float4 bj = cbx[q * 64 + jj];
        if (jg > i && jg < NPRE && iou_gt(bi, bj)) bits |= (1ull << jj);
      }
      M[(size_t)i * MROW + w] = bits;
    }
    __syncthreads();
  }
}

// ---------------- K10b: serial greedy resolve (1 wave) ----------------
__global__ __launch_bounds__(64) void resolve_kernel(const unsigned long long* __restrict__ M,
                                                     const Ctl* __restrict__ ctl,
                                                     const float4* __restrict__ sbox,
                                                     float* __restrict__ rois_out) {
  __shared__ unsigned long long remLDS[94];
  __shared__ int keepList[NPOST];
  __shared__ int keepCount;
  const int l = threadIdx.x;
  unsigned cnt = ctl->candCount; if (cnt > (unsigned)NPRE) cnt = NPRE;
  const int nvalid = (int)cnt;

  auto initw = [&](int w) -> unsigned long long {
    int lo = w * 64;
    if (lo + 64 <= nvalid) return 0ull;
    if (lo >= nvalid) return ~0ull;
    return (~0ull) << (nvalid - lo);
  };
  unsigned long long rem0 = initw(l);
  unsigned long long rem1 = (l < 30) ? initw(64 + l) : ~0ull;

  auto loadg = [&](int g, unsigned long long* m0, unsigned long long* m1) {
    #pragma unroll
    for (int r = 0; r < 8; ++r) {
      int i = g * 8 + r;
      if (i < NPRE) {
        m0[r] = M[(size_t)i * MROW + l];
        m1[r] = (l < 30) ? M[(size_t)i * MROW + 64 + l] : 0ull;
      } else { m0[r] = 0ull; m1[r] = 0ull; }
    }
  };
  auto procg = [&](int g, unsigned long long* m0, unsigned long long* m1) {
    #pragma unroll
    for (int r = 0; r < 8; ++r) {
      int i = g * 8 + r;
      int ci = i >> 6, bit = i & 63;
      unsigned long long wv = (ci < 64) ? rem0 : rem1;
      int owner = (ci < 64) ? ci : (ci - 64);
      int rbit = __shfl((int)((wv >> bit) & 1ull), owner);
      if (!rbit) {
        rem0 |= (l >= ci) ? m0[r] : 0ull;
        rem1 |= ((64 + l) >= ci) ? m1[r] : 0ull;
      }
    }
  };

  unsigned long long A0[8], A1[8], B0[8], B1[8], C0[8], C1[8], D0[8], D1[8];
  loadg(0, A0, A1); loadg(1, B0, B1); loadg(2, C0, C1); loadg(3, D0, D1);
  for (int g = 0; g < 752; g += 4) {
    procg(g,     A0, A1); if (g + 4 < 752) loadg(g + 4, A0, A1);
    procg(g + 1, B0, B1); if (g + 5 < 752) loadg(g + 5, B0, B1);
    procg(g + 2, C0, C1); if (g + 6 < 752) loadg(g + 6, C0, C1);
    procg(g + 3, D0, D1); if (g + 7 < 752) loadg(g + 7, D0, D1);
  }

  remLDS[l] = rem0;
  if (l < 30) remLDS[64 + l] = rem1;
  __syncthreads();
  if (l == 0) {
    int ck = 0;
    for (int w = 0; w < 94 && ck < NPOST; ++w) {
      unsigned long long kw = ~remLDS[w];
      while (kw && ck < NPOST) {
        int r = __ffsll((long long)kw) - 1; kw &= kw - 1;
        keepList[ck++] = w * 64 + r;
      }
    }
    keepCount = ck;
  }
  __syncthreads();
  for (int s = l; s < NPOST; s += 64) {
    float4 b = make_float4(0.f, 0.f, 0.f, 0.f);
    if (s < keepCount) b = sbox[keepList[s]];
    *(float4*)&rois_out[(size_t)s * 4] = b;
  }
}

// ---------------- host ----------------
extern "C" void kernel_launch(void* const* d_in, const int* in_sizes, int n_in,
                              void* d_out, int out_size, void* d_ws, size_t ws_size,
                              hipStream_t stream) {
  const float* x  = (const float*)d_in[0];
  const float* w1 = (const float*)d_in[1];
  const float* b1 = (const float*)d_in[2];
  const float* sw = (const float*)d_in[3];
  const float* sb = (const float*)d_in[4];
  const float* lw = (const float*)d_in[5];
  const float* lb = (const float*)d_in[6];
  const int* ihp  = (const int*)d_in[7];
  const int* iwp  = (const int*)d_in[8];
  float* out = (float*)d_out;

  char* ws = (char*)d_ws;
  _Float16* wtapH = (_Float16*)(ws + WTH_OFF);
  _Float16* wtapL = (_Float16*)(ws + WTL_OFF);
  float* wx   = (float*)(ws + WX_OFF);
  _Float16* xh_alloc = (_Float16*)(ws + XH_OFF);
  _Float16* xl_alloc = (_Float16*)(ws + XL_OFF);
  _Float16* xh = xh_alloc + (size_t)XGUARD * 512;   // guarded base: row index = pp
  _Float16* xl = xl_alloc + (size_t)XGUARD * 512;
  float* h    = (float*)(ws + H_OFF);
  float* roi  = (float*)(ws + ROI_OFF);
  float* sc   = (float*)(ws + SC_OFF);
  Ctl*   ctl  = (Ctl*)(ws + CTL_OFF);
  unsigned long long* cand = (unsigned long long*)(ws + CAND_OFF);
  float4* sbox = (float4*)(ws + SBOX_OFF);
  unsigned long long* Mmask = (unsigned long long*)(ws + H_OFF);  // reuse h region after heads

  AnchorArg ab;
  {
    const double ratios[3] = {0.5, 1.0, 2.0};
    const double scales[3] = {8.0, 16.0, 32.0};
    for (int i = 0; i < 3; ++i)
      for (int j = 0; j < 3; ++j) {
        double hh = 16.0 * scales[j] * sqrt(ratios[i]);
        double wwd = 16.0 * scales[j] * sqrt(1.0 / ratios[i]);
        int a = i * 3 + j;
        ab.v[a * 4 + 0] = (float)(8.0 - hh / 2.0);
        ab.v[a * 4 + 1] = (float)(8.0 - wwd / 2.0);
        ab.v[a * 4 + 2] = (float)(8.0 + hh / 2.0);
        ab.v[a * 4 + 3] = (float)(8.0 + wwd / 2.0);
      }
  }

  float* rpn_loc   = out;                 // 136800*4
  float* rpn_score = out + 547200;        // 136800*2
  float* rois      = out + 820800;        // 300*4

  wx_kernel<<<108, 256, 0, stream>>>(sw, lw, wx, ctl);
  prep_w_kernel<<<512, 256, 0, stream>>>(w1, wtapH, wtapL);
  prep_x_kernel<<<XROWS_TOTAL / 64, 256, 0, stream>>>(x, xh_alloc, xl_alloc);
  conv1_mfma_kernel<<<dim3(PPS / 128, 4), 256, 0, stream>>>(xh, xl, wtapH, wtapL, b1, h);
  heads_kernel<<<238, 256, 0, stream>>>(h, wx, sb, lb, rpn_loc, rpn_score, roi, sc, ab, ihp, iwp);
  for (int p = 0; p < 3; ++p) {
    hist_pass<<<120, 256, 0, stream>>>(sc, ctl, p);
    scan_pass<<<1, 256, 0, stream>>>(ctl);
  }
  compact_kernel<<<535, 256, 0, stream>>>(sc, ctl, cand);
  sort_kernel<<<1, 1024, 0, stream>>>(cand, ctl, roi, sbox);
  mask_kernel<<<94, 256, 0, stream>>>(sbox, Mmask);
  resolve_kernel<<<1, 64, 0, stream>>>(Mmask, ctl, sbox, rois);
}

// Round 4
// 888.095 us; speedup vs baseline: 5.4326x; 2.0373x over previous
//
#include <hip/hip_runtime.h>
#include <math.h>
#include <stdint.h>

// ---------------- problem constants ----------------
#define CHH 100
#define CWW 152
#define NPIX 15200          // 100*152
#define NANCH 136800        // NPIX*9
#define NPRE 6000
#define NPOST 300
#define CANDCAP 8192
#define MROW 96             // u64 words per mask row (94 used, padded)

// padded pixel geometry for the MFMA conv: pp = (py+1)*154 + (px+1)
#define PSTRIDE 154
#define PPVALID 16016       // 154*104 region containing all shifted accesses
#define PPS 16128           // padded to 126 tiles of 128
#define XGUARD 256          // zero guard rows each side of the [0,PPS) range
#define XROWS_TOTAL (PPS + 2*XGUARD)   // 16640

// ---------------- ws layout (bytes) ----------------
#define WTH_OFF  0ull                  // w taps hi: [9][512][512] f16 = 4,718,592
#define WTL_OFF  4718592ull            // w taps lo
#define WX_OFF   9437184ull            // 1x1 weights transposed: [512][54] f32
#define XH_OFF   9547776ull            // x hi plane: [16640][512] f16 = 17,039,360
#define XL_OFF   26587136ull           // x lo plane
#define H_OFF    43626496ull           // hidden: [512][16128] f32 = 33,030,144 (reused as NMS mask)
#define ROI_OFF  76656640ull           // roi: [136800][4] f32
#define SC_OFF   78845440ull           // sc: [136800] f32
#define CTL_OFF  79392640ull           // Ctl struct
#define CAND_OFF 79396736ull           // cand: [8192] u64
#define SBOX_OFF 79462272ull           // sorted boxes: [6000] float4

typedef _Float16 f16x8 __attribute__((ext_vector_type(8)));
typedef float    f32x4 __attribute__((ext_vector_type(4)));

struct Ctl {
  unsigned hist[256];
  unsigned prefix;
  unsigned countGreater;
  unsigned candCount;
  unsigned pad;
};

struct AnchorArg { float v[36]; };

__device__ __forceinline__ unsigned mono_key(float f) {
  unsigned u = __float_as_uint(f);
  return u ^ ((u & 0x80000000u) ? 0xFFFFFFFFu : 0x80000000u);
}

// ---------------- K1: combined 1x1 weights + ctl init ----------------
__global__ void wx_kernel(const float* __restrict__ score_w, const float* __restrict__ loc_w,
                          float* __restrict__ wx, Ctl* __restrict__ ctl) {
  int i = blockIdx.x * 256 + threadIdx.x;
  if (blockIdx.x == 0) {
    int t = threadIdx.x;
    ctl->hist[t] = 0u;
    if (t == 0) { ctl->prefix = 0u; ctl->countGreater = 0u; ctl->candCount = 0u; }
  }
  if (i >= 512 * 54) return;
  int ic = i / 54, oc = i - ic * 54;
  wx[i] = (oc < 18) ? score_w[oc * 512 + ic] : loc_w[(oc - 18) * 512 + ic];
}

// ---------------- K2: split conv1 weights into per-tap f16 hi/lo planes ----------------
__global__ __launch_bounds__(256) void prep_w_kernel(const float* __restrict__ w1,
                                                     _Float16* __restrict__ wtapH,
                                                     _Float16* __restrict__ wtapL) {
  __shared__ float wl[4608];
  const int oc = blockIdx.x, tid = threadIdx.x;
  for (int li = tid; li < 4608; li += 256) wl[li] = w1[(size_t)oc * 4608 + li];
  __syncthreads();
  for (int t = 0; t < 9; ++t) {
    size_t ob = ((size_t)t * 512 + oc) * 512;
    for (int ic = tid; ic < 512; ic += 256) {
      float v = wl[ic * 9 + t];
      _Float16 hi = (_Float16)v;
      wtapH[ob + ic] = hi;
      wtapL[ob + ic] = (_Float16)(v - (float)hi);
    }
  }
}

// ---------------- K3: transpose+pad+split input: x [512][15200] -> xh/xl [16640][512] ----
__global__ __launch_bounds__(256) void prep_x_kernel(const float* __restrict__ x,
                                                     _Float16* __restrict__ xh,
                                                     _Float16* __restrict__ xl) {
  __shared__ float tile[64][65];
  const int tid = threadIdx.x;
  const int r0 = blockIdx.x * 64;                // alloc-row base (0..16640)
  for (int ic0 = 0; ic0 < 512; ic0 += 64) {
    #pragma unroll
    for (int it = 0; it < 16; ++it) {
      int li = it * 256 + tid;
      int i = li >> 6, j = li & 63;
      int pp = r0 + j - XGUARD;
      float v = 0.f;
      if (pp >= 0 && pp < PPVALID) {
        int rowp = pp / PSTRIDE, colp = pp - rowp * PSTRIDE;
        if (rowp >= 1 && rowp <= 100 && colp >= 1 && colp <= 152) {
          int p = (rowp - 1) * CWW + (colp - 1);
          v = x[(size_t)(ic0 + i) * NPIX + p];
        }
      }
      tile[i][j] = v;
    }
    __syncthreads();
    int j = tid >> 2, cq = tid & 3;
    size_t ob = (size_t)(r0 + j) * 512 + ic0 + cq * 16;
    #pragma unroll
    for (int c = 0; c < 16; ++c) {
      float v = tile[cq * 16 + c][j];
      _Float16 hi = (_Float16)v;
      xh[ob + c] = hi;
      xl[ob + c] = (_Float16)(v - (float)hi);
    }
    __syncthreads();
  }
}

// ---------------- K4: conv1 as split-f16 MFMA implicit GEMM ----------------
__global__ __launch_bounds__(256) void conv1_mfma_kernel(const _Float16* __restrict__ xh,
                                                         const _Float16* __restrict__ xl,
                                                         const _Float16* __restrict__ wtapH,
                                                         const _Float16* __restrict__ wtapL,
                                                         const float* __restrict__ bias,
                                                         float* __restrict__ h) {
  __shared__ _Float16 Ah[128][32], Al[128][32], Bh[128][32], Bl[128][32];
  __shared__ float bsm[128];
  const int tid = threadIdx.x;
  const int pp0 = blockIdx.x * 128;
  const int oc0 = blockIdx.y * 128;
  if (tid < 128) bsm[tid] = bias[oc0 + tid];

  const int lane = tid & 63;
  const int n16 = lane & 15, quad = lane >> 4;
  const int wid = tid >> 6;
  const int wm = wid >> 1, wn = wid & 1;
  const int srow = tid >> 2, sq = tid & 3;

  f32x4 acc[4][4];
  #pragma unroll
  for (int mi = 0; mi < 4; ++mi)
    #pragma unroll
    for (int ni = 0; ni < 4; ++ni) acc[mi][ni] = (f32x4){0.f, 0.f, 0.f, 0.f};

  for (int t = 0; t < 9; ++t) {
    const int dsh = (t / 3 - 1) * PSTRIDE + (t % 3) - 1;
    const size_t wbase = ((size_t)t * 512 + oc0) * 512;
    for (int icb = 0; icb < 512; icb += 32) {
      #pragma unroll
      for (int hf = 0; hf < 2; ++hf) {
        int row = hf * 64 + srow;
        size_t wo = wbase + (size_t)row * 512 + icb + sq * 8;
        *(f16x8*)&Ah[row][sq * 8] = *(const f16x8*)&wtapH[wo];
        *(f16x8*)&Al[row][sq * 8] = *(const f16x8*)&wtapL[wo];
        size_t xo = (size_t)(pp0 + row + dsh) * 512 + icb + sq * 8;
        *(f16x8*)&Bh[row][sq * 8] = *(const f16x8*)&xh[xo];
        *(f16x8*)&Bl[row][sq * 8] = *(const f16x8*)&xl[xo];
      }
      __syncthreads();
      f16x8 ah[4], al[4], bh[4], bl[4];
      #pragma unroll
      for (int mi = 0; mi < 4; ++mi) {
        ah[mi] = *(const f16x8*)&Ah[wm * 64 + mi * 16 + n16][quad * 8];
        al[mi] = *(const f16x8*)&Al[wm * 64 + mi * 16 + n16][quad * 8];
      }
      #pragma unroll
      for (int ni = 0; ni < 4; ++ni) {
        bh[ni] = *(const f16x8*)&Bh[wn * 64 + ni * 16 + n16][quad * 8];
        bl[ni] = *(const f16x8*)&Bl[wn * 64 + ni * 16 + n16][quad * 8];
      }
      #pragma unroll
      for (int mi = 0; mi < 4; ++mi)
        #pragma unroll
        for (int ni = 0; ni < 4; ++ni) {
          acc[mi][ni] = __builtin_amdgcn_mfma_f32_16x16x32_f16(ah[mi], bh[ni], acc[mi][ni], 0, 0, 0);
          acc[mi][ni] = __builtin_amdgcn_mfma_f32_16x16x32_f16(ah[mi], bl[ni], acc[mi][ni], 0, 0, 0);
          acc[mi][ni] = __builtin_amdgcn_mfma_f32_16x16x32_f16(al[mi], bh[ni], acc[mi][ni], 0, 0, 0);
        }
      __syncthreads();
    }
  }
  #pragma unroll
  for (int mi = 0; mi < 4; ++mi) {
    int ocb = wm * 64 + mi * 16 + quad * 4;
    #pragma unroll
    for (int ni = 0; ni < 4; ++ni) {
      int pp = pp0 + wn * 64 + ni * 16 + n16;
      #pragma unroll
      for (int r = 0; r < 4; ++r) {
        float v = acc[mi][ni][r] + bsm[ocb + r];
        h[(size_t)(oc0 + ocb + r) * PPS + pp] = fmaxf(v, 0.f);
      }
    }
  }
}

// ---------------- K5: 1x1 heads + softmax + loc2bbox + clip + valid ----------------
__global__ __launch_bounds__(256) void heads_kernel(const float* __restrict__ h,
                                                    const float* __restrict__ wx,
                                                    const float* __restrict__ score_b,
                                                    const float* __restrict__ loc_b,
                                                    float* __restrict__ rpn_loc,
                                                    float* __restrict__ rpn_score,
                                                    float* __restrict__ roi,
                                                    float* __restrict__ sc,
                                                    AnchorArg ab,
                                                    const int* __restrict__ ihp,
                                                    const int* __restrict__ iwp) {
  __shared__ float hs[64][64];
  __shared__ float red[54][64];
  const int tid = threadIdx.x;
  const int p0 = blockIdx.x * 64;
  const int pxl = tid & 63, icq = tid >> 6;
  int pcol = p0 + pxl;
  bool pok = pcol < NPIX;
  int ppl = 0;
  if (pok) ppl = (pcol / CWW + 1) * PSTRIDE + (pcol % CWW) + 1;

  float acc[54];
  #pragma unroll
  for (int o = 0; o < 54; ++o) acc[o] = 0.f;

  for (int c = 0; c < 8; ++c) {
    int ic0 = c * 64;
    #pragma unroll
    for (int r = 0; r < 16; ++r) {
      int i = r * 4 + icq;
      hs[i][pxl] = pok ? h[(size_t)(ic0 + i) * PPS + ppl] : 0.f;
    }
    __syncthreads();
    #pragma unroll
    for (int k = 0; k < 16; ++k) {
      int icl = icq + k * 4;
      float v = hs[icl][pxl];
      const float* wrow = &wx[(ic0 + icl) * 54];
      #pragma unroll
      for (int o = 0; o < 54; ++o) acc[o] += wrow[o] * v;
    }
    __syncthreads();
  }
  for (int w = 0; w < 4; ++w) {
    if (icq == w) {
      if (w == 0) {
        #pragma unroll
        for (int o = 0; o < 54; ++o) red[o][pxl] = acc[o];
      } else {
        #pragma unroll
        for (int o = 0; o < 54; ++o) red[o][pxl] += acc[o];
      }
    }
    __syncthreads();
  }

  const float fH = (float)(*ihp);
  const float fW = (float)(*iwp);
  for (int it = tid; it < 576; it += 256) {
    #pragma clang fp contract(off)
    int pl = it / 9, a = it - pl * 9;
    int p = p0 + pl;
    if (p >= NPIX) continue;
    float s0 = red[a * 2][pl]     + score_b[a * 2];
    float s1 = red[a * 2 + 1][pl] + score_b[a * 2 + 1];
    float dy = red[18 + a * 4][pl]     + loc_b[a * 4];
    float dx = red[18 + a * 4 + 1][pl] + loc_b[a * 4 + 1];
    float dh = red[18 + a * 4 + 2][pl] + loc_b[a * 4 + 2];
    float dw = red[18 + a * 4 + 3][pl] + loc_b[a * 4 + 3];
    int row = p * 9 + a;
    *(float2*)&rpn_score[row * 2] = make_float2(s0, s1);
    *(float4*)&rpn_loc[(size_t)row * 4] = make_float4(dy, dx, dh, dw);
    int ypix = p / CWW, xpix = p - ypix * CWW;
    float sy = (float)(ypix * 16), sx = (float)(xpix * 16);
    float a0 = sy + ab.v[a * 4 + 0], a1 = sx + ab.v[a * 4 + 1];
    float a2 = sy + ab.v[a * 4 + 2], a3 = sx + ab.v[a * 4 + 3];
    float ha = a2 - a0, wa = a3 - a1;
    float cy = a0 + 0.5f * ha, cx = a1 + 0.5f * wa;
    float cy2 = dy * ha + cy, cx2 = dx * wa + cx;
    float h2 = expf(dh) * ha, w2 = expf(dw) * wa;
    float y1 = cy2 - 0.5f * h2, x1 = cx2 - 0.5f * w2;
    float y2 = cy2 + 0.5f * h2, x2 = cx2 + 0.5f * w2;
    y1 = fminf(fmaxf(y1, 0.f), fH); x1 = fminf(fmaxf(x1, 0.f), fW);
    y2 = fminf(fmaxf(y2, 0.f), fH); x2 = fminf(fmaxf(x2, 0.f), fW);
    *(float4*)&roi[(size_t)row * 4] = make_float4(y1, x1, y2, x2);
    bool valid = (y2 - y1 >= 16.f) && (x2 - x1 >= 16.f);
    float m  = fmaxf(s0, s1);
    float e0 = expf(s0 - m), e1 = expf(s1 - m);
    float fg = e1 / (e0 + e1);
    sc[row] = valid ? fg : -__builtin_inff();
  }
}

// ---------------- K6/K7: radix-select ----------------
__global__ __launch_bounds__(256) void hist_pass(const float* __restrict__ sc,
                                                 Ctl* __restrict__ ctl, int pass) {
  __shared__ unsigned hloc[256];
  int tid = threadIdx.x;
  hloc[tid] = 0u;
  __syncthreads();
  unsigned prefix = ctl->prefix;
  for (int i = blockIdx.x * 256 + tid; i < NANCH; i += gridDim.x * 256) {
    unsigned m = mono_key(sc[i]);
    bool pred = (pass == 0) || ((m >> (32 - 8 * pass)) == prefix);
    if (pred) atomicAdd(&hloc[(m >> (24 - 8 * pass)) & 255u], 1u);
  }
  __syncthreads();
  if (hloc[tid]) atomicAdd(&ctl->hist[tid], hloc[tid]);
}

__global__ void scan_pass(Ctl* __restrict__ ctl) {
  __shared__ unsigned s[256];
  int t = threadIdx.x;
  s[t] = ctl->hist[t];
  ctl->hist[t] = 0u;
  __syncthreads();
  for (int d = 1; d < 256; d <<= 1) {
    unsigned v = s[t] + ((t + d < 256) ? s[t + d] : 0u);
    __syncthreads();
    s[t] = v;
    __syncthreads();
  }
  unsigned G = ctl->countGreater;
  unsigned inclT = s[t];
  unsigned inclN = (t < 255) ? s[t + 1] : 0u;
  if (G + inclT >= (unsigned)NPRE && G + inclN < (unsigned)NPRE) {
    ctl->prefix = (ctl->prefix << 8) | (unsigned)t;
    ctl->countGreater = G + inclN;
  }
}

// ---------------- K8: compact candidates ----------------
__global__ __launch_bounds__(256) void compact_kernel(const float* __restrict__ sc,
                                                      Ctl* __restrict__ ctl,
                                                      unsigned long long* __restrict__ cand) {
  int i = blockIdx.x * 256 + threadIdx.x;
  unsigned prefix = ctl->prefix;
  bool pred = false; unsigned m = 0;
  if (i < NANCH) { m = mono_key(sc[i]); pred = ((m >> 8) >= prefix); }
  unsigned long long mask = __ballot(pred);
  if (mask) {
    int lane = threadIdx.x & 63;
    int leader = __ffsll((long long)mask) - 1;
    unsigned base = 0;
    if (lane == leader) base = atomicAdd(&ctl->candCount, (unsigned)__popcll(mask));
    base = __shfl(base, leader);
    if (pred) {
      unsigned slot = base + (unsigned)__popcll(mask & ((1ull << lane) - 1ull));
      if (slot < CANDCAP)
        cand[slot] = (((unsigned long long)(~m)) << 32) | (unsigned)i;
    }
  }
}

// ---------------- K9: single-block bitonic sort; gather boxes ----------------
__global__ __launch_bounds__(1024) void sort_kernel(const unsigned long long* __restrict__ cand,
                                                    const Ctl* __restrict__ ctl,
                                                    const float* __restrict__ roi,
                                                    float4* __restrict__ sbox) {
  __shared__ unsigned long long s[8192];
  int tid = threadIdx.x;
  unsigned cnt = ctl->candCount; if (cnt > CANDCAP) cnt = CANDCAP;
  #pragma unroll
  for (int r = 0; r < 8; ++r) {
    int i = r * 1024 + tid;
    s[i] = (i < (int)cnt) ? cand[i] : ~0ull;
  }
  __syncthreads();
  for (int k = 2; k <= 8192; k <<= 1)
    for (int j = k >> 1; j > 0; j >>= 1) {
      #pragma unroll
      for (int r = 0; r < 8; ++r) {
        int i = r * 1024 + tid; int l = i ^ j;
        if (l > i) {
          unsigned long long a = s[i], b = s[l];
          bool up = ((i & k) == 0);
          if ((a > b) == up) { s[i] = b; s[l] = a; }
        }
      }
      __syncthreads();
    }
  #pragma unroll
  for (int r = 0; r < 6; ++r) {
    int i = r * 1024 + tid;
    if (i < NPRE) {
      unsigned idx = (unsigned)(s[i] & 0xFFFFFFFFull);
      float4 b = make_float4(0.f, 0.f, 0.f, 0.f);
      if (idx < (unsigned)NANCH) b = *(const float4*)&roi[(size_t)idx * 4];
      sbox[i] = b;
    }
  }
}

// ---------------- K10a: parallel IoU mask matrix ----------------
__device__ __forceinline__ bool iou_gt(float4 A, float4 B) {
  float areaA = (A.z - A.x) * (A.w - A.y);
  float areaB = (B.z - B.x) * (B.w - B.y);
  float ih = fmaxf(fminf(A.z, B.z) - fmaxf(A.x, B.x), 0.f);
  float iw = fmaxf(fminf(A.w, B.w) - fmaxf(A.y, B.y), 0.f);
  float inter = ih * iw;
  return inter / (areaA + areaB - inter + 1e-9f) > 0.7f;
}

__global__ __launch_bounds__(256) void mask_kernel(const float4* __restrict__ sbox,
                                                   unsigned long long* __restrict__ M) {
  __shared__ float4 rb[64];
  __shared__ float4 cbx[256];
  const int c = blockIdx.x;
  const int tid = threadIdx.x;
  if (tid < 64) {
    int i = c * 64 + tid;
    rb[tid] = (i < NPRE) ? sbox[i] : make_float4(0.f, 0.f, 0.f, 0.f);
  }
  __syncthreads();
  const int rl = tid >> 2, q = tid & 3;
  const int i = c * 64 + rl;
  const float4 bi = rb[rl];
  for (int t = c >> 2; t < 24; ++t) {
    int j = t * 256 + tid;
    cbx[tid] = (j < NPRE) ? sbox[j] : make_float4(0.f, 0.f, 0.f, 0.f);
    __syncthreads();
    int w = t * 4 + q;
    if (w >= c && i < NPRE) {
      unsigned long long bits = 0ull;
      #pragma unroll 8
      for (int jj = 0; jj < 64; ++jj) {
        int jg = w * 64 + jj;
        float4 bj = cbx[q * 64 + jj];
        if (jg > i && jg < NPRE && iou_gt(bi, bj)) bits |= (1ull << jj);
      }
      M[(size_t)i * MROW + w] = bits;
    }
    __syncthreads();
  }
}

// ---------------- K10b: serial greedy resolve, v2 ----------------
// Replicated-word intra-chunk VALU chain + distributed cross-chunk OR + early exit at 300 keeps.
__global__ __launch_bounds__(64) void resolve_kernel(const unsigned long long* __restrict__ M,
                                                     const Ctl* __restrict__ ctl,
                                                     const float4* __restrict__ sbox,
                                                     float* __restrict__ rois_out) {
  __shared__ unsigned long long remLDS[94];
  __shared__ int keepList[NPOST];
  __shared__ int keepCount;
  const int l = threadIdx.x;
  unsigned cnt = ctl->candCount; if (cnt > (unsigned)NPRE) cnt = NPRE;
  const int nvalid = (int)cnt;

  auto initw = [&](int w) -> unsigned long long {
    int lo = w * 64;
    if (lo + 64 <= nvalid) return 0ull;
    if (lo >= nvalid) return ~0ull;
    return (~0ull) << (nvalid - lo);
  };
  unsigned long long rem0 = initw(l);                         // word l
  unsigned long long rem1 = (l < 30) ? initw(64 + l) : ~0ull; // word 64+l (94..127 unused)

  int keepTotal = 0;
  int cstop = 94;
  // lane l holds diag word of row c*64+l for the current chunk; prefetch chunk 0
  unsigned long long dw = M[(size_t)l * MROW + 0];

  for (int c = 0; c < 94; ++c) {
    // prefetch next chunk's diagonal word (independent of the serial chain)
    unsigned long long dwN = 0ull;
    if (c + 1 < 94) dwN = M[(size_t)((c + 1) * 64 + l) * MROW + (c + 1)];

    // broadcast rem word c into all lanes
    unsigned long long remRep = (c < 64) ? __shfl(rem0, c) : __shfl(rem1, c - 64);

    // intra-chunk serial greedy: pure-VALU chain, shfl broadcasts hoisted in batches of 16
    #pragma unroll
    for (int kk = 0; kk < 64; kk += 16) {
      unsigned long long wv[16];
      #pragma unroll
      for (int t = 0; t < 16; ++t) wv[t] = __shfl(dw, kk + t);
      #pragma unroll
      for (int t = 0; t < 16; ++t) {
        if (!((remRep >> (kk + t)) & 1ull)) remRep |= wv[t];
      }
    }

    if (l == 0) remLDS[c] = remRep;
    if (c < 64) { if (l == c) rem0 = remRep; }
    else        { if (l == c - 64) rem1 = remRep; }
    keepTotal += (int)__popcll(~remRep);

    // cross-chunk suppression: OR kept rows' mask words into distributed rem, 4 rows/batch
    unsigned long long km = ~remRep;
    const size_t base = (size_t)c * 64;
    while (km) {
      int k0 = __ffsll((long long)km) - 1; km &= km - 1;
      int k1 = k0, k2 = k0, k3 = k0;
      if (km) { k1 = __ffsll((long long)km) - 1; km &= km - 1; }
      if (km) { k2 = __ffsll((long long)km) - 1; km &= km - 1; }
      if (km) { k3 = __ffsll((long long)km) - 1; km &= km - 1; }
      const unsigned long long* p0 = M + (base + k0) * MROW;
      const unsigned long long* p1 = M + (base + k1) * MROW;
      const unsigned long long* p2 = M + (base + k2) * MROW;
      const unsigned long long* p3 = M + (base + k3) * MROW;
      unsigned long long a0 = p0[l], a1 = p1[l], a2 = p2[l], a3 = p3[l];
      rem0 |= a0 | a1 | a2 | a3;
      if (l < 30) {
        unsigned long long b0 = p0[64 + l], b1 = p1[64 + l], b2 = p2[64 + l], b3 = p3[64 + l];
        rem1 |= b0 | b1 | b2 | b3;
      }
    }

    dw = dwN;
    if (keepTotal >= NPOST) { cstop = c + 1; break; }   // first 300 keeps found
  }

  __syncthreads();
  if (l == 0) {
    int ck = 0;
    for (int w = 0; w < cstop && ck < NPOST; ++w) {
      unsigned long long kw = ~remLDS[w];
      while (kw && ck < NPOST) {
        int r = __ffsll((long long)kw) - 1; kw &= kw - 1;
        keepList[ck++] = w * 64 + r;
      }
    }
    keepCount = ck;
  }
  __syncthreads();
  for (int s = l; s < NPOST; s += 64) {
    float4 b = make_float4(0.f, 0.f, 0.f, 0.f);
    if (s < keepCount) b = sbox[keepList[s]];
    *(float4*)&rois_out[(size_t)s * 4] = b;
  }
}

// ---------------- host ----------------
extern "C" void kernel_launch(void* const* d_in, const int* in_sizes, int n_in,
                              void* d_out, int out_size, void* d_ws, size_t ws_size,
                              hipStream_t stream) {
  const float* x  = (const float*)d_in[0];
  const float* w1 = (const float*)d_in[1];
  const float* b1 = (const float*)d_in[2];
  const float* sw = (const float*)d_in[3];
  const float* sb = (const float*)d_in[4];
  const float* lw = (const float*)d_in[5];
  const float* lb = (const float*)d_in[6];
  const int* ihp  = (const int*)d_in[7];
  const int* iwp  = (const int*)d_in[8];
  float* out = (float*)d_out;

  char* ws = (char*)d_ws;
  _Float16* wtapH = (_Float16*)(ws + WTH_OFF);
  _Float16* wtapL = (_Float16*)(ws + WTL_OFF);
  float* wx   = (float*)(ws + WX_OFF);
  _Float16* xh_alloc = (_Float16*)(ws + XH_OFF);
  _Float16* xl_alloc = (_Float16*)(ws + XL_OFF);
  _Float16* xh = xh_alloc + (size_t)XGUARD * 512;
  _Float16* xl = xl_alloc + (size_t)XGUARD * 512;
  float* h    = (float*)(ws + H_OFF);
  float* roi  = (float*)(ws + ROI_OFF);
  float* sc   = (float*)(ws + SC_OFF);
  Ctl*   ctl  = (Ctl*)(ws + CTL_OFF);
  unsigned long long* cand = (unsigned long long*)(ws + CAND_OFF);
  float4* sbox = (float4*)(ws + SBOX_OFF);
  unsigned long long* Mmask = (unsigned long long*)(ws + H_OFF);

  AnchorArg ab;
  {
    const double ratios[3] = {0.5, 1.0, 2.0};
    const double scales[3] = {8.0, 16.0, 32.0};
    for (int i = 0; i < 3; ++i)
      for (int j = 0; j < 3; ++j) {
        double hh = 16.0 * scales[j] * sqrt(ratios[i]);
        double wwd = 16.0 * scales[j] * sqrt(1.0 / ratios[i]);
        int a = i * 3 + j;
        ab.v[a * 4 + 0] = (float)(8.0 - hh / 2.0);
        ab.v[a * 4 + 1] = (float)(8.0 - wwd / 2.0);
        ab.v[a * 4 + 2] = (float)(8.0 + hh / 2.0);
        ab.v[a * 4 + 3] = (float)(8.0 + wwd / 2.0);
      }
  }

  float* rpn_loc   = out;                 // 136800*4
  float* rpn_score = out + 547200;        // 136800*2
  float* rois      = out + 820800;        // 300*4

  wx_kernel<<<108, 256, 0, stream>>>(sw, lw, wx, ctl);
  prep_w_kernel<<<512, 256, 0, stream>>>(w1, wtapH, wtapL);
  prep_x_kernel<<<XROWS_TOTAL / 64, 256, 0, stream>>>(x, xh_alloc, xl_alloc);
  conv1_mfma_kernel<<<dim3(PPS / 128, 4), 256, 0, stream>>>(xh, xl, wtapH, wtapL, b1, h);
  heads_kernel<<<238, 256, 0, stream>>>(h, wx, sb, lb, rpn_loc, rpn_score, roi, sc, ab, ihp, iwp);
  for (int p = 0; p < 3; ++p) {
    hist_pass<<<120, 256, 0, stream>>>(sc, ctl, p);
    scan_pass<<<1, 256, 0, stream>>>(ctl);
  }
  compact_kernel<<<535, 256, 0, stream>>>(sc, ctl, cand);
  sort_kernel<<<1, 1024, 0, stream>>>(cand, ctl, roi, sbox);
  mask_kernel<<<94, 256, 0, stream>>>(sbox, Mmask);
  resolve_kernel<<<1, 64, 0, stream>>>(Mmask, ctl, sbox, rois);
}